// Round 4
// baseline (10874.211 us; speedup 1.0000x reference)
//
#include <hip/hip_runtime.h>

#define B_ROWS  4096
#define D_DIM   512
#define H_DIM   2048
#define N_STEPS 32
#define EPS_CONV 0.01f
#define LN_EPSF  1e-5f

typedef __attribute__((ext_vector_type(4))) float f32x4;
typedef __attribute__((ext_vector_type(8))) _Float16 h16x8;
typedef unsigned short ushort_t;
typedef unsigned int uint32;

__device__ __forceinline__ float wave_reduce_sum(float v) {
#pragma unroll
  for (int o = 32; o > 0; o >>= 1) v += __shfl_down(v, o, 64);
  return v;
}

__device__ __forceinline__ float gelu_exact(float v) {
  return 0.5f * v * (1.0f + erff(v * 0.7071067811865476f));
}

// pack fp32 -> u32 = lo16<<16 | hi16  (hi = f16(v), lo = f16((v-hi)*1024))
__device__ __forceinline__ uint32 pack_split(float v) {
  const _Float16 hi = (_Float16)v;
  const _Float16 lo = (_Float16)((v - (float)hi) * 1024.0f);
  union { _Float16 f[2]; uint32 u; } c;
  c.f[0] = hi; c.f[1] = lo;
  return c.u;
}

// MFMA-fragment-tiled index: [row/16][k/32][row&15][(k>>3)&3][k&7], 512 u32/tile
__device__ __forceinline__ size_t amap(int row, int k, int K) {
  return ((size_t)((row >> 4) * (K >> 5) + (k >> 5)) << 9) +
         ((row & 15) << 5) + (((k >> 3) & 3) << 3) + (k & 7);
}

// ============ LayerNorm -> packed hi/lo f16, fragment-tiled ================
__global__ __launch_bounds__(256)
void ln_pack_kernel(const float* in, const float* in2, const float* g,
                    const float* b, uint32* outp) {
  const int row = blockIdx.x;
  const int t = threadIdx.x;
  float2 v = ((const float2*)(in + (size_t)row * D_DIM))[t];
  if (in2 != nullptr) {
    const float2 w = ((const float2*)(in2 + (size_t)row * D_DIM))[t];
    v.x += w.x; v.y += w.y;
  }
  float s  = v.x + v.y;
  float sq = v.x * v.x + v.y * v.y;
  s  = wave_reduce_sum(s);
  sq = wave_reduce_sum(sq);
  __shared__ float sd1[4], sd2[4], mb[2];
  const int lane = t & 63, wid = t >> 6;
  if (lane == 0) { sd1[wid] = s; sd2[wid] = sq; }
  __syncthreads();
  if (t == 0) {
    float st = sd1[0] + sd1[1] + sd1[2] + sd1[3];
    float qt = sd2[0] + sd2[1] + sd2[2] + sd2[3];
    float mean = st * (1.0f / (float)D_DIM);
    float var  = qt * (1.0f / (float)D_DIM) - mean * mean;
    mb[0] = mean;
    mb[1] = rsqrtf(var + LN_EPSF);
  }
  __syncthreads();
  const float mean = mb[0], rstd = mb[1];
  const float2 gv = ((const float2*)g)[t];
  const float2 bv = ((const float2*)b)[t];
  uint2 o;
  o.x = pack_split((v.x - mean) * rstd * gv.x + bv.x);
  o.y = pack_split((v.y - mean) * rstd * gv.y + bv.y);
  *(uint2*)(outp + amap(row, 2 * t, D_DIM)) = o;
}

// ============ weight transpose + split + pack + tile =======================
// w [K][N] fp32 -> wp [N][K] packed u32, fragment-tiled.
__global__ __launch_bounds__(256)
void transpose_split_kernel(const float* __restrict__ w,
                            uint32* __restrict__ wp, int K, int N) {
  __shared__ float t[32][33];
  const int tx = threadIdx.x;   // 0..31
  const int ty = threadIdx.y;   // 0..7
  const int n_base = blockIdx.x * 32;
  const int k_base = blockIdx.y * 32;
#pragma unroll
  for (int r = 0; r < 4; ++r)
    t[ty + r * 8][tx] = w[(size_t)(k_base + ty + r * 8) * N + n_base + tx];
  __syncthreads();
#pragma unroll
  for (int r = 0; r < 4; ++r) {
    const int n = n_base + ty + r * 8;
    const int k = k_base + tx;
    wp[amap(n, k, K)] = pack_split(t[tx][ty + r * 8]);
  }
}

// ============ LDS-free direct-to-VGPR f16x3 MFMA GEMM ======================
// A: packed u32, fragment-tiled [M][K]; W: packed u32, fragment-tiled [N][K].
// BM=128, BK=32, 4 waves 2x2 (wave tile 64 x BN/2). No LDS, no barriers.
// OUT_PACK: Cp = pack(gelu(acc+bias)), fragment-tiled [M][N] (K-layout of the
// next GEMM). else: fp32 partial to C0 (z==0, +bias) / C1 (z==1), row-major.
template <int BN, bool OUT_PACK>
__global__ __launch_bounds__(256, 2)
void gemm_direct(const uint32* __restrict__ Ap, const uint32* __restrict__ Wp,
                 const float* __restrict__ bias, uint32* __restrict__ Cp,
                 float* __restrict__ C0, float* __restrict__ C1,
                 int M, int N, int K, int kc) {
  constexpr int FN = BN / 32;      // n-frags per wave
  const int KT = K >> 5;           // k-tiles
  const int NKT = kc >> 5;         // k-tiles this block processes

  const int tid = threadIdx.x;
  const int lane = tid & 63;
  const int wid = tid >> 6;
  const int q = lane >> 4;         // 0..3
  const int l16 = lane & 15;
  const int wm = wid >> 1;         // 0..1
  const int wn = wid & 1;          // 0..1

  const int m0 = blockIdx.x * 128;
  const int n0 = blockIdx.y * BN;
  const int kt0 = blockIdx.z * NKT;

  const int loff = l16 * 32 + q * 8;

  // per-fragment global base offsets (u32 units); advance by 512 per k-tile
  const uint32* pa[4];
#pragma unroll
  for (int i = 0; i < 4; ++i) {
    const int tm = (m0 >> 4) + wm * 4 + i;
    pa[i] = Ap + ((size_t)(tm * KT + kt0) << 9) + loff;
  }
  const uint32* pb[FN];
#pragma unroll
  for (int j = 0; j < FN; ++j) {
    const int tn = (n0 >> 4) + wn * FN + j;
    pb[j] = Wp + ((size_t)(tn * KT + kt0) << 9) + loff;
  }

  f32x4 acc_h[4][FN], acc_m[4][FN];
#pragma unroll
  for (int i = 0; i < 4; ++i)
#pragma unroll
    for (int j = 0; j < FN; ++j) {
      acc_h[i][j] = (f32x4){0.f, 0.f, 0.f, 0.f};
      acc_m[i][j] = (f32x4){0.f, 0.f, 0.f, 0.f};
    }

  for (int kt = 0; kt < NKT; ++kt) {
    // ---- raw fragment loads (2 x dwordx4 each, contiguous 2KB tiles) ----
    uint4 ca0[4], ca1[4], cb0[FN], cb1[FN];
#pragma unroll
    for (int i = 0; i < 4; ++i) {
      ca0[i] = *(const uint4*)(pa[i]);
      ca1[i] = *(const uint4*)(pa[i] + 4);
      pa[i] += 512;
    }
#pragma unroll
    for (int j = 0; j < FN; ++j) {
      cb0[j] = *(const uint4*)(pb[j]);
      cb1[j] = *(const uint4*)(pb[j] + 4);
      pb[j] += 512;
    }
    // ---- unpack hi/lo via v_perm ----
    h16x8 ah[4], al[4], bh[FN], bl[FN];
#pragma unroll
    for (int i = 0; i < 4; ++i) {
      union { uint32 u[4]; h16x8 h; } hu, lu;
      hu.u[0] = __builtin_amdgcn_perm(ca0[i].y, ca0[i].x, 0x05040100u);
      hu.u[1] = __builtin_amdgcn_perm(ca0[i].w, ca0[i].z, 0x05040100u);
      hu.u[2] = __builtin_amdgcn_perm(ca1[i].y, ca1[i].x, 0x05040100u);
      hu.u[3] = __builtin_amdgcn_perm(ca1[i].w, ca1[i].z, 0x05040100u);
      lu.u[0] = __builtin_amdgcn_perm(ca0[i].y, ca0[i].x, 0x07060302u);
      lu.u[1] = __builtin_amdgcn_perm(ca0[i].w, ca0[i].z, 0x07060302u);
      lu.u[2] = __builtin_amdgcn_perm(ca1[i].y, ca1[i].x, 0x07060302u);
      lu.u[3] = __builtin_amdgcn_perm(ca1[i].w, ca1[i].z, 0x07060302u);
      ah[i] = hu.h; al[i] = lu.h;
    }
#pragma unroll
    for (int j = 0; j < FN; ++j) {
      union { uint32 u[4]; h16x8 h; } hu, lu;
      hu.u[0] = __builtin_amdgcn_perm(cb0[j].y, cb0[j].x, 0x05040100u);
      hu.u[1] = __builtin_amdgcn_perm(cb0[j].w, cb0[j].z, 0x05040100u);
      hu.u[2] = __builtin_amdgcn_perm(cb1[j].y, cb1[j].x, 0x05040100u);
      hu.u[3] = __builtin_amdgcn_perm(cb1[j].w, cb1[j].z, 0x05040100u);
      lu.u[0] = __builtin_amdgcn_perm(cb0[j].y, cb0[j].x, 0x07060302u);
      lu.u[1] = __builtin_amdgcn_perm(cb0[j].w, cb0[j].z, 0x07060302u);
      lu.u[2] = __builtin_amdgcn_perm(cb1[j].y, cb1[j].x, 0x07060302u);
      lu.u[3] = __builtin_amdgcn_perm(cb1[j].w, cb1[j].z, 0x07060302u);
      bh[j] = hu.h; bl[j] = lu.h;
    }
    // ---- 3-term MFMA ----
#pragma unroll
    for (int i = 0; i < 4; ++i)
#pragma unroll
      for (int j = 0; j < FN; ++j) {
        acc_h[i][j] = __builtin_amdgcn_mfma_f32_16x16x32_f16(ah[i], bh[j], acc_h[i][j], 0, 0, 0);
        acc_m[i][j] = __builtin_amdgcn_mfma_f32_16x16x32_f16(al[i], bh[j], acc_m[i][j], 0, 0, 0);
        acc_m[i][j] = __builtin_amdgcn_mfma_f32_16x16x32_f16(ah[i], bl[j], acc_m[i][j], 0, 0, 0);
      }
  }

  // ---- epilogue ----
#pragma unroll
  for (int i = 0; i < 4; ++i) {
    const int row = m0 + wm * 64 + i * 16 + q * 4;
#pragma unroll
    for (int j = 0; j < FN; ++j) {
      const int col = n0 + wn * (BN / 2) + j * 16 + l16;
      if (OUT_PACK) {
        const float bv = bias[col];
#pragma unroll
        for (int r = 0; r < 4; ++r) {
          float v = acc_h[i][j][r] + acc_m[i][j][r] * (1.0f / 1024.0f) + bv;
          Cp[amap(row + r, col, N)] = pack_split(gelu_exact(v));
        }
      } else {
        float* C = (blockIdx.z == 0) ? C0 : C1;
        const float bv = (blockIdx.z == 0) ? bias[col] : 0.0f;
#pragma unroll
        for (int r = 0; r < 4; ++r) {
          C[(size_t)(row + r) * N + col] =
              acc_h[i][j][r] + acc_m[i][j][r] * (1.0f / 1024.0f) + bv;
        }
      }
    }
  }
}

// ============ update: z += (d0+d1) unless converged ========================
__global__ __launch_bounds__(256)
void update_kernel(float* __restrict__ z, const float* __restrict__ d0,
                   const float* __restrict__ d1, int* __restrict__ mask) {
  const int row = blockIdx.x;
  const int t = threadIdx.x;
  float2 d = ((const float2*)(d0 + (size_t)row * D_DIM))[t];
  const float2 e = ((const float2*)(d1 + (size_t)row * D_DIM))[t];
  d.x += e.x; d.y += e.y;
  float sq = d.x * d.x + d.y * d.y;
  sq = wave_reduce_sum(sq);
  __shared__ float sd[4];
  __shared__ int frozen_sh;
  const int lane = t & 63, wid = t >> 6;
  if (lane == 0) sd[wid] = sq;
  __syncthreads();
  if (t == 0) {
    const float dist = sqrtf(sd[0] + sd[1] + sd[2] + sd[3]);
    const int m = mask[row];
    const int newly = (dist < EPS_CONV) ? 1 : 0;
    if (!m && newly) mask[row] = 1;
    frozen_sh = m | newly;
  }
  __syncthreads();
  if (!frozen_sh) {
    float2* zp = (float2*)(z + (size_t)row * D_DIM);
    float2 zv = zp[t];
    zv.x += d.x; zv.y += d.y;
    zp[t] = zv;
  }
}

__global__ __launch_bounds__(256)
void final_kernel(const float* __restrict__ z, const float* __restrict__ clf_w,
                  const float* __restrict__ clf_b, const int* __restrict__ mask,
                  float* __restrict__ logits, float* __restrict__ maskf) {
  const int row = blockIdx.x;
  const int t = threadIdx.x;
  const float2 zv = ((const float2*)(z + (size_t)row * D_DIM))[t];
  const float2 wv = ((const float2*)clf_w)[t];
  float s = zv.x * wv.x + zv.y * wv.y;
  s = wave_reduce_sum(s);
  __shared__ float sd[4];
  const int lane = t & 63, wid = t >> 6;
  if (lane == 0) sd[wid] = s;
  __syncthreads();
  if (t == 0) {
    logits[row] = sd[0] + sd[1] + sd[2] + sd[3] + clf_b[0];
    maskf[row] = mask[row] ? 1.0f : 0.0f;
  }
}

__global__ void init_kernel(const float* __restrict__ z_init,
                            float* __restrict__ z, int* __restrict__ mask,
                            int n) {
  const int i = blockIdx.x * blockDim.x + threadIdx.x;
  if (i < n) z[i] = z_init[i];
  if (i < B_ROWS) mask[i] = 0;
}

// ============ fp32 fallback (only if ws too small) =========================
__global__ __launch_bounds__(256)
void ln_f32_kernel(const float* __restrict__ in, const float* __restrict__ g,
                   const float* __restrict__ b, float* __restrict__ out) {
  const int row = blockIdx.x;
  const int t = threadIdx.x;
  const float2 v = ((const float2*)(in + (size_t)row * D_DIM))[t];
  float s = v.x + v.y, sq = v.x * v.x + v.y * v.y;
  s = wave_reduce_sum(s); sq = wave_reduce_sum(sq);
  __shared__ float sd1[4], sd2[4], mb[2];
  const int lane = t & 63, wid = t >> 6;
  if (lane == 0) { sd1[wid] = s; sd2[wid] = sq; }
  __syncthreads();
  if (t == 0) {
    float st = sd1[0] + sd1[1] + sd1[2] + sd1[3];
    float qt = sd2[0] + sd2[1] + sd2[2] + sd2[3];
    float mean = st / (float)D_DIM;
    float var = qt / (float)D_DIM - mean * mean;
    mb[0] = mean; mb[1] = rsqrtf(var + LN_EPSF);
  }
  __syncthreads();
  const float mean = mb[0], rstd = mb[1];
  const float2 gv = ((const float2*)g)[t];
  const float2 bv = ((const float2*)b)[t];
  float2 r;
  r.x = (v.x - mean) * rstd * gv.x + bv.x;
  r.y = (v.y - mean) * rstd * gv.y + bv.y;
  ((float2*)(out + (size_t)row * D_DIM))[t] = r;
}

__global__ __launch_bounds__(256)
void update_f32_kernel(float* __restrict__ z, const float* __restrict__ delta,
                       int* __restrict__ mask) {
  const int row = blockIdx.x;
  const int t = threadIdx.x;
  const float2 d = ((const float2*)(delta + (size_t)row * D_DIM))[t];
  float sq = d.x * d.x + d.y * d.y;
  sq = wave_reduce_sum(sq);
  __shared__ float sd[4];
  __shared__ int frozen_sh;
  const int lane = t & 63, wid = t >> 6;
  if (lane == 0) sd[wid] = sq;
  __syncthreads();
  if (t == 0) {
    const float dist = sqrtf(sd[0] + sd[1] + sd[2] + sd[3]);
    const int m = mask[row];
    const int newly = (dist < EPS_CONV) ? 1 : 0;
    if (!m && newly) mask[row] = 1;
    frozen_sh = m | newly;
  }
  __syncthreads();
  if (!frozen_sh) {
    float2* zp = (float2*)(z + (size_t)row * D_DIM);
    float2 zv = zp[t];
    zv.x += d.x; zv.y += d.y;
    zp[t] = zv;
  }
}

template <int BM, int BN>
__global__ __launch_bounds__(256)
void gemm_fp32_fallback(const float* __restrict__ A, const float* __restrict__ W,
                        const float* __restrict__ bias, float* __restrict__ C,
                        int M, int N, int K, int do_gelu) {
  constexpr int BK = 8;
  constexpr int TM = BM / 16;
  constexpr int TN = BN / 16;
  __shared__ float As[BK][BM];
  __shared__ float Bs[BK][BN];
  const int tid = threadIdx.x;
  const int m0 = blockIdx.x * BM;
  const int n0 = blockIdx.y * BN;
  const int ty = tid >> 4, tx = tid & 15;
  float acc[TM][TN];
#pragma unroll
  for (int i = 0; i < TM; ++i)
#pragma unroll
    for (int j = 0; j < TN; ++j) acc[i][j] = 0.0f;
  for (int k0 = 0; k0 < K; k0 += BK) {
    if constexpr (BM == 128) {
      const int row = tid >> 1, col = (tid & 1) * 4;
      const float4 a = *(const float4*)(A + (size_t)(m0 + row) * K + k0 + col);
      As[col + 0][row] = a.x; As[col + 1][row] = a.y;
      As[col + 2][row] = a.z; As[col + 3][row] = a.w;
    } else {
      const int row = tid >> 2, col = (tid & 3) * 2;
      const float2 a = *(const float2*)(A + (size_t)(m0 + row) * K + k0 + col);
      As[col + 0][row] = a.x; As[col + 1][row] = a.y;
    }
    {
      const int row = tid >> 5, col = (tid & 31) * 4;
      const float4 w = *(const float4*)(W + (size_t)(k0 + row) * N + n0 + col);
      *(float4*)(&Bs[row][col]) = w;
    }
    __syncthreads();
#pragma unroll
    for (int kk = 0; kk < BK; ++kk) {
      float a[TM], b[TN];
#pragma unroll
      for (int i = 0; i < TM; i += 4)
        *(float4*)(a + i) = *(const float4*)(&As[kk][ty * TM + i]);
#pragma unroll
      for (int j = 0; j < TN; j += 4)
        *(float4*)(b + j) = *(const float4*)(&Bs[kk][tx * TN + j]);
#pragma unroll
      for (int i = 0; i < TM; ++i)
#pragma unroll
        for (int j = 0; j < TN; ++j) acc[i][j] = fmaf(a[i], b[j], acc[i][j]);
    }
    __syncthreads();
  }
  float bv[TN];
#pragma unroll
  for (int j = 0; j < TN; ++j) bv[j] = bias[n0 + tx * TN + j];
#pragma unroll
  for (int i = 0; i < TM; ++i) {
    const int r = m0 + ty * TM + i;
#pragma unroll
    for (int j = 0; j < TN; j += 4) {
      float4 v;
      v.x = acc[i][j + 0] + bv[j + 0]; v.y = acc[i][j + 1] + bv[j + 1];
      v.z = acc[i][j + 2] + bv[j + 2]; v.w = acc[i][j + 3] + bv[j + 3];
      if (do_gelu) {
        v.x = gelu_exact(v.x); v.y = gelu_exact(v.y);
        v.z = gelu_exact(v.z); v.w = gelu_exact(v.w);
      }
      *(float4*)(C + (size_t)r * N + n0 + tx * TN + j) = v;
    }
  }
}

// ============ launch =======================================================
extern "C" void kernel_launch(void* const* d_in, const int* in_sizes, int n_in,
                              void* d_out, int out_size, void* d_ws,
                              size_t ws_size, hipStream_t stream) {
  const float* z_init = (const float*)d_in[0];
  const float* ln1_g  = (const float*)d_in[1];
  const float* ln1_b  = (const float*)d_in[2];
  const float* w1     = (const float*)d_in[3];
  const float* b1     = (const float*)d_in[4];
  const float* w2     = (const float*)d_in[5];
  const float* b2     = (const float*)d_in[6];
  const float* ln2_g  = (const float*)d_in[7];
  const float* ln2_b  = (const float*)d_in[8];
  const float* w3     = (const float*)d_in[9];
  const float* b3     = (const float*)d_in[10];
  const float* w4     = (const float*)d_in[11];
  const float* b4     = (const float*)d_in[12];
  const float* clf_w  = (const float*)d_in[13];
  const float* clf_b  = (const float*)d_in[14];

  float* out    = (float*)d_out;
  float* logits = out;
  float* maskf  = out + B_ROWS;
  float* z      = out + 2 * B_ROWS;   // [B,D] in d_out

  const size_t BD = (size_t)B_ROWS * D_DIM;
  const size_t BH = (size_t)B_ROWS * H_DIM;
  const size_t WSZ = (size_t)D_DIM * H_DIM;

  // layout: xp | hp | y | w1p..w4p | mask | p1
  uint32* xp  = (uint32*)d_ws;          // [B,D] packed tiled
  uint32* hp  = xp + BD;                // [B,H] packed tiled
  float*  y   = (float*)(hp + BH);      // [B,D] fp32 split-K chunk 0
  uint32* w1p = (uint32*)(y + BD);      // each WSZ u32, packed tiled [N][K]
  uint32* w2p = w1p + WSZ;
  uint32* w3p = w2p + WSZ;
  uint32* w4p = w3p + WSZ;
  int*    mask = (int*)(w4p + WSZ);
  float*  p1  = (float*)(mask + B_ROWS); // [B,D] fp32 split-K chunk 1
  const size_t need = (uintptr_t)((char*)(p1 + BD) - (char*)d_ws) + 256;

  init_kernel<<<(int)((BD + 255) / 256), 256, 0, stream>>>(z_init, z, mask,
                                                           (int)BD);

  if (ws_size >= need) {
    const dim3 tb(32, 8);
    transpose_split_kernel<<<dim3(H_DIM / 32, D_DIM / 32), tb, 0, stream>>>(w1, w1p, D_DIM, H_DIM);
    transpose_split_kernel<<<dim3(D_DIM / 32, H_DIM / 32), tb, 0, stream>>>(w2, w2p, H_DIM, D_DIM);
    transpose_split_kernel<<<dim3(H_DIM / 32, D_DIM / 32), tb, 0, stream>>>(w3, w3p, D_DIM, H_DIM);
    transpose_split_kernel<<<dim3(D_DIM / 32, H_DIM / 32), tb, 0, stream>>>(w4, w4p, H_DIM, D_DIM);

    const dim3 g_up(B_ROWS / 128, H_DIM / 128, 1);   // 512 blocks
    const dim3 g_dn(B_ROWS / 128, D_DIM / 64, 2);    // 512 blocks, split-K=2
    for (int s = 0; s < N_STEPS; ++s) {
      ln_pack_kernel<<<B_ROWS, 256, 0, stream>>>(z, nullptr, ln1_g, ln1_b, xp);
      gemm_direct<128, true><<<g_up, 256, 0, stream>>>(
          xp, w1p, b1, hp, nullptr, nullptr, B_ROWS, H_DIM, D_DIM, D_DIM);
      gemm_direct<64, false><<<g_dn, 256, 0, stream>>>(
          hp, w2p, b2, nullptr, y, p1, B_ROWS, D_DIM, H_DIM, H_DIM / 2);
      ln_pack_kernel<<<B_ROWS, 256, 0, stream>>>(y, p1, ln2_g, ln2_b, xp);
      gemm_direct<128, true><<<g_up, 256, 0, stream>>>(
          xp, w3p, b3, hp, nullptr, nullptr, B_ROWS, H_DIM, D_DIM, D_DIM);
      gemm_direct<64, false><<<g_dn, 256, 0, stream>>>(
          hp, w4p, b4, nullptr, y, p1, B_ROWS, D_DIM, H_DIM, H_DIM / 2);
      update_kernel<<<B_ROWS, 256, 0, stream>>>(z, y, p1, mask);
    }
  } else {
    // fallback: fp32 pipeline
    float* x  = (float*)d_ws;
    float* yf = x + BD;
    float* h  = yf + BD;
    int* mask_fb = (int*)(h + BH);
    mask = mask_fb;
    const dim3 g_up(B_ROWS / 128, H_DIM / 128);
    const dim3 g_dn(B_ROWS / 64, D_DIM / 128);
    for (int s = 0; s < N_STEPS; ++s) {
      ln_f32_kernel<<<B_ROWS, 256, 0, stream>>>(z, ln1_g, ln1_b, x);
      gemm_fp32_fallback<128, 128><<<g_up, 256, 0, stream>>>(x, w1, b1, h, B_ROWS, H_DIM, D_DIM, 1);
      gemm_fp32_fallback<64, 128><<<g_dn, 256, 0, stream>>>(h, w2, b2, yf, B_ROWS, D_DIM, H_DIM, 0);
      ln_f32_kernel<<<B_ROWS, 256, 0, stream>>>(yf, ln2_g, ln2_b, x);
      gemm_fp32_fallback<128, 128><<<g_up, 256, 0, stream>>>(x, w3, b3, h, B_ROWS, H_DIM, D_DIM, 1);
      gemm_fp32_fallback<64, 128><<<g_dn, 256, 0, stream>>>(h, w4, b4, yf, B_ROWS, D_DIM, H_DIM, 0);
      update_f32_kernel<<<B_ROWS, 256, 0, stream>>>(z, yf, mask);
    }
  }
  final_kernel<<<B_ROWS, 256, 0, stream>>>(z, clf_w, clf_b, mask, logits, maskf);
}

// Round 5
// 6466.098 us; speedup vs baseline: 1.6817x; 1.6817x over previous
//
#include <hip/hip_runtime.h>

#define B_ROWS  4096
#define D_DIM   512
#define H_DIM   2048
#define N_STEPS 32
#define EPS_CONV 0.01f
#define LN_EPSF  1e-5f

typedef __attribute__((ext_vector_type(4))) float f32x4;
typedef __attribute__((ext_vector_type(8))) _Float16 h16x8;
typedef unsigned short ushort_t;
typedef unsigned int uint32;

__device__ __forceinline__ float wave_reduce_sum(float v) {
#pragma unroll
  for (int o = 32; o > 0; o >>= 1) v += __shfl_down(v, o, 64);
  return v;
}

__device__ __forceinline__ float gelu_exact(float v) {
  return 0.5f * v * (1.0f + erff(v * 0.7071067811865476f));
}

// pack fp32 -> u32 = lo16<<16 | hi16  (hi = f16(v), lo = f16((v-hi)*1024))
__device__ __forceinline__ uint32 pack_split(float v) {
  const _Float16 hi = (_Float16)v;
  const _Float16 lo = (_Float16)((v - (float)hi) * 1024.0f);
  union { _Float16 f[2]; uint32 u; } c;
  c.f[0] = hi; c.f[1] = lo;
  return c.u;
}

// Lane-contiguous MFMA fragment tiling (u32 elems):
//   tile = (row>>4)*(K>>5) + (k>>5)          (16 rows x 32 k per tile)
//   lane = ((k>>3)&3)*16 + (row&15)          (MFMA lane = q*16 + l16)
//   half = (k>>2)&1                          (each lane: 2 x 16B halves)
//   off  = tile*512 + half*256 + lane*4 + (k&3)
// GEMM fragment load = two fully lane-coalesced 1KB dwordx4 loads.
__device__ __forceinline__ size_t amap(int row, int k, int K) {
  return ((size_t)((row >> 4) * (K >> 5) + (k >> 5)) << 9) +
         (((k >> 2) & 1) << 8) +
         (((((k >> 3) & 3) << 4) + (row & 15)) << 2) + (k & 3);
}

// ============ LayerNorm -> packed hi/lo f16, fragment-tiled ================
__global__ __launch_bounds__(256)
void ln_pack_kernel(const float* in, const float* in2, const float* g,
                    const float* b, uint32* outp) {
  const int row = blockIdx.x;
  const int t = threadIdx.x;
  float2 v = ((const float2*)(in + (size_t)row * D_DIM))[t];
  if (in2 != nullptr) {
    const float2 w = ((const float2*)(in2 + (size_t)row * D_DIM))[t];
    v.x += w.x; v.y += w.y;
  }
  float s  = v.x + v.y;
  float sq = v.x * v.x + v.y * v.y;
  s  = wave_reduce_sum(s);
  sq = wave_reduce_sum(sq);
  __shared__ float sd1[4], sd2[4], mb[2];
  const int lane = t & 63, wid = t >> 6;
  if (lane == 0) { sd1[wid] = s; sd2[wid] = sq; }
  __syncthreads();
  if (t == 0) {
    float st = sd1[0] + sd1[1] + sd1[2] + sd1[3];
    float qt = sd2[0] + sd2[1] + sd2[2] + sd2[3];
    float mean = st * (1.0f / (float)D_DIM);
    float var  = qt * (1.0f / (float)D_DIM) - mean * mean;
    mb[0] = mean;
    mb[1] = rsqrtf(var + LN_EPSF);
  }
  __syncthreads();
  const float mean = mb[0], rstd = mb[1];
  const float2 gv = ((const float2*)g)[t];
  const float2 bv = ((const float2*)b)[t];
  uint2 o;
  o.x = pack_split((v.x - mean) * rstd * gv.x + bv.x);
  o.y = pack_split((v.y - mean) * rstd * gv.y + bv.y);
  // k=2t,2t+1 share a 4-elem group -> contiguous uint2 store
  *(uint2*)(outp + amap(row, 2 * t, D_DIM)) = o;
}

// ============ weight transpose + split + pack + tile (one-time) ============
__global__ __launch_bounds__(256)
void transpose_split_kernel(const float* __restrict__ w,
                            uint32* __restrict__ wp, int K, int N) {
  __shared__ float t[32][33];
  const int tx = threadIdx.x;   // 0..31
  const int ty = threadIdx.y;   // 0..7
  const int n_base = blockIdx.x * 32;
  const int k_base = blockIdx.y * 32;
#pragma unroll
  for (int r = 0; r < 4; ++r)
    t[ty + r * 8][tx] = w[(size_t)(k_base + ty + r * 8) * N + n_base + tx];
  __syncthreads();
#pragma unroll
  for (int r = 0; r < 4; ++r) {
    const int n = n_base + ty + r * 8;
    const int k = k_base + tx;
    wp[amap(n, k, K)] = pack_split(t[tx][ty + r * 8]);
  }
}

// ============ LDS-free direct-to-VGPR f16x3 MFMA GEMM ======================
// A, W: packed u32 in lane-contiguous fragment tiles. BM=128, BK=32,
// 4 waves 2x2 (wave tile 64 x BN/2). No LDS, no barriers in the K-loop.
template <int BN, bool OUT_PACK>
__global__ __launch_bounds__(256, 2)
void gemm_direct(const uint32* __restrict__ Ap, const uint32* __restrict__ Wp,
                 const float* __restrict__ bias, uint32* __restrict__ Cp,
                 float* __restrict__ C0, float* __restrict__ C1,
                 int M, int N, int K, int kc) {
  constexpr int FN = BN / 32;      // n-frags per wave
  const int KT = K >> 5;           // k-tiles total
  const int NKT = kc >> 5;         // k-tiles this block

  const int tid = threadIdx.x;
  const int lane = tid & 63;
  const int wid = tid >> 6;
  const int q = lane >> 4;
  const int l16 = lane & 15;
  const int wm = wid >> 1;
  const int wn = wid & 1;

  const int m0 = blockIdx.x * 128;
  const int n0 = blockIdx.y * BN;
  const int kt0 = blockIdx.z * NKT;

  const int loff = lane * 4;       // lane-contiguous: 64 lanes x 16B = 1KB

  const uint32* pa[4];
#pragma unroll
  for (int i = 0; i < 4; ++i) {
    const int tm = (m0 >> 4) + wm * 4 + i;
    pa[i] = Ap + ((size_t)(tm * KT + kt0) << 9) + loff;
  }
  const uint32* pb[FN];
#pragma unroll
  for (int j = 0; j < FN; ++j) {
    const int tn = (n0 >> 4) + wn * FN + j;
    pb[j] = Wp + ((size_t)(tn * KT + kt0) << 9) + loff;
  }

  f32x4 acc_h[4][FN], acc_m[4][FN];
#pragma unroll
  for (int i = 0; i < 4; ++i)
#pragma unroll
    for (int j = 0; j < FN; ++j) {
      acc_h[i][j] = (f32x4){0.f, 0.f, 0.f, 0.f};
      acc_m[i][j] = (f32x4){0.f, 0.f, 0.f, 0.f};
    }

  for (int kt = 0; kt < NKT; ++kt) {
    // ---- fragment loads: 2 coalesced 1KB dwordx4 per fragment ----
    uint4 ca0[4], ca1[4], cb0[FN], cb1[FN];
#pragma unroll
    for (int i = 0; i < 4; ++i) {
      ca0[i] = *(const uint4*)(pa[i]);         // k = q*8 + 0..3
      ca1[i] = *(const uint4*)(pa[i] + 256);   // k = q*8 + 4..7
      pa[i] += 512;
    }
#pragma unroll
    for (int j = 0; j < FN; ++j) {
      cb0[j] = *(const uint4*)(pb[j]);
      cb1[j] = *(const uint4*)(pb[j] + 256);
      pb[j] += 512;
    }
    // ---- unpack hi/lo via v_perm ----
    h16x8 ah[4], al[4], bh[FN], bl[FN];
#pragma unroll
    for (int i = 0; i < 4; ++i) {
      union { uint32 u[4]; h16x8 h; } hu, lu;
      hu.u[0] = __builtin_amdgcn_perm(ca0[i].y, ca0[i].x, 0x05040100u);
      hu.u[1] = __builtin_amdgcn_perm(ca0[i].w, ca0[i].z, 0x05040100u);
      hu.u[2] = __builtin_amdgcn_perm(ca1[i].y, ca1[i].x, 0x05040100u);
      hu.u[3] = __builtin_amdgcn_perm(ca1[i].w, ca1[i].z, 0x05040100u);
      lu.u[0] = __builtin_amdgcn_perm(ca0[i].y, ca0[i].x, 0x07060302u);
      lu.u[1] = __builtin_amdgcn_perm(ca0[i].w, ca0[i].z, 0x07060302u);
      lu.u[2] = __builtin_amdgcn_perm(ca1[i].y, ca1[i].x, 0x07060302u);
      lu.u[3] = __builtin_amdgcn_perm(ca1[i].w, ca1[i].z, 0x07060302u);
      ah[i] = hu.h; al[i] = lu.h;
    }
#pragma unroll
    for (int j = 0; j < FN; ++j) {
      union { uint32 u[4]; h16x8 h; } hu, lu;
      hu.u[0] = __builtin_amdgcn_perm(cb0[j].y, cb0[j].x, 0x05040100u);
      hu.u[1] = __builtin_amdgcn_perm(cb0[j].w, cb0[j].z, 0x05040100u);
      hu.u[2] = __builtin_amdgcn_perm(cb1[j].y, cb1[j].x, 0x05040100u);
      hu.u[3] = __builtin_amdgcn_perm(cb1[j].w, cb1[j].z, 0x05040100u);
      lu.u[0] = __builtin_amdgcn_perm(cb0[j].y, cb0[j].x, 0x07060302u);
      lu.u[1] = __builtin_amdgcn_perm(cb0[j].w, cb0[j].z, 0x07060302u);
      lu.u[2] = __builtin_amdgcn_perm(cb1[j].y, cb1[j].x, 0x07060302u);
      lu.u[3] = __builtin_amdgcn_perm(cb1[j].w, cb1[j].z, 0x07060302u);
      bh[j] = hu.h; bl[j] = lu.h;
    }
    // ---- 3-term MFMA ----
#pragma unroll
    for (int i = 0; i < 4; ++i)
#pragma unroll
      for (int j = 0; j < FN; ++j) {
        acc_h[i][j] = __builtin_amdgcn_mfma_f32_16x16x32_f16(ah[i], bh[j], acc_h[i][j], 0, 0, 0);
        acc_m[i][j] = __builtin_amdgcn_mfma_f32_16x16x32_f16(al[i], bh[j], acc_m[i][j], 0, 0, 0);
        acc_m[i][j] = __builtin_amdgcn_mfma_f32_16x16x32_f16(ah[i], bl[j], acc_m[i][j], 0, 0, 0);
      }
  }

  // ---- epilogue ----
#pragma unroll
  for (int i = 0; i < 4; ++i) {
    const int row = m0 + wm * 64 + i * 16 + q * 4;
#pragma unroll
    for (int j = 0; j < FN; ++j) {
      const int col = n0 + wn * (BN / 2) + j * 16 + l16;
      if (OUT_PACK) {
        const float bv = bias[col];
#pragma unroll
        for (int r = 0; r < 4; ++r) {
          float v = acc_h[i][j][r] + acc_m[i][j][r] * (1.0f / 1024.0f) + bv;
          Cp[amap(row + r, col, N)] = pack_split(gelu_exact(v));
        }
      } else {
        float* C = (blockIdx.z == 0) ? C0 : C1;
        const float bv = (blockIdx.z == 0) ? bias[col] : 0.0f;
#pragma unroll
        for (int r = 0; r < 4; ++r) {
          C[(size_t)(row + r) * N + col] =
              acc_h[i][j][r] + acc_m[i][j][r] * (1.0f / 1024.0f) + bv;
        }
      }
    }
  }
}

// ============ update: z += (d0+d1) unless converged ========================
__global__ __launch_bounds__(256)
void update_kernel(float* __restrict__ z, const float* __restrict__ d0,
                   const float* __restrict__ d1, int* __restrict__ mask) {
  const int row = blockIdx.x;
  const int t = threadIdx.x;
  float2 d = ((const float2*)(d0 + (size_t)row * D_DIM))[t];
  const float2 e = ((const float2*)(d1 + (size_t)row * D_DIM))[t];
  d.x += e.x; d.y += e.y;
  float sq = d.x * d.x + d.y * d.y;
  sq = wave_reduce_sum(sq);
  __shared__ float sd[4];
  __shared__ int frozen_sh;
  const int lane = t & 63, wid = t >> 6;
  if (lane == 0) sd[wid] = sq;
  __syncthreads();
  if (t == 0) {
    const float dist = sqrtf(sd[0] + sd[1] + sd[2] + sd[3]);
    const int m = mask[row];
    const int newly = (dist < EPS_CONV) ? 1 : 0;
    if (!m && newly) mask[row] = 1;
    frozen_sh = m | newly;
  }
  __syncthreads();
  if (!frozen_sh) {
    float2* zp = (float2*)(z + (size_t)row * D_DIM);
    float2 zv = zp[t];
    zv.x += d.x; zv.y += d.y;
    zp[t] = zv;
  }
}

__global__ __launch_bounds__(256)
void final_kernel(const float* __restrict__ z, const float* __restrict__ clf_w,
                  const float* __restrict__ clf_b, const int* __restrict__ mask,
                  float* __restrict__ logits, float* __restrict__ maskf) {
  const int row = blockIdx.x;
  const int t = threadIdx.x;
  const float2 zv = ((const float2*)(z + (size_t)row * D_DIM))[t];
  const float2 wv = ((const float2*)clf_w)[t];
  float s = zv.x * wv.x + zv.y * wv.y;
  s = wave_reduce_sum(s);
  __shared__ float sd[4];
  const int lane = t & 63, wid = t >> 6;
  if (lane == 0) sd[wid] = s;
  __syncthreads();
  if (t == 0) {
    logits[row] = sd[0] + sd[1] + sd[2] + sd[3] + clf_b[0];
    maskf[row] = mask[row] ? 1.0f : 0.0f;
  }
}

__global__ void init_kernel(const float* __restrict__ z_init,
                            float* __restrict__ z, int* __restrict__ mask,
                            int n) {
  const int i = blockIdx.x * blockDim.x + threadIdx.x;
  if (i < n) z[i] = z_init[i];
  if (i < B_ROWS) mask[i] = 0;
}

// ============ fp32 fallback (only if ws too small) =========================
__global__ __launch_bounds__(256)
void ln_f32_kernel(const float* __restrict__ in, const float* __restrict__ g,
                   const float* __restrict__ b, float* __restrict__ out) {
  const int row = blockIdx.x;
  const int t = threadIdx.x;
  const float2 v = ((const float2*)(in + (size_t)row * D_DIM))[t];
  float s = v.x + v.y, sq = v.x * v.x + v.y * v.y;
  s = wave_reduce_sum(s); sq = wave_reduce_sum(sq);
  __shared__ float sd1[4], sd2[4], mb[2];
  const int lane = t & 63, wid = t >> 6;
  if (lane == 0) { sd1[wid] = s; sd2[wid] = sq; }
  __syncthreads();
  if (t == 0) {
    float st = sd1[0] + sd1[1] + sd1[2] + sd1[3];
    float qt = sd2[0] + sd2[1] + sd2[2] + sd2[3];
    float mean = st / (float)D_DIM;
    float var = qt / (float)D_DIM - mean * mean;
    mb[0] = mean; mb[1] = rsqrtf(var + LN_EPSF);
  }
  __syncthreads();
  const float mean = mb[0], rstd = mb[1];
  const float2 gv = ((const float2*)g)[t];
  const float2 bv = ((const float2*)b)[t];
  float2 r;
  r.x = (v.x - mean) * rstd * gv.x + bv.x;
  r.y = (v.y - mean) * rstd * gv.y + bv.y;
  ((float2*)(out + (size_t)row * D_DIM))[t] = r;
}

__global__ __launch_bounds__(256)
void update_f32_kernel(float* __restrict__ z, const float* __restrict__ delta,
                       int* __restrict__ mask) {
  const int row = blockIdx.x;
  const int t = threadIdx.x;
  const float2 d = ((const float2*)(delta + (size_t)row * D_DIM))[t];
  float sq = d.x * d.x + d.y * d.y;
  sq = wave_reduce_sum(sq);
  __shared__ float sd[4];
  __shared__ int frozen_sh;
  const int lane = t & 63, wid = t >> 6;
  if (lane == 0) sd[wid] = sq;
  __syncthreads();
  if (t == 0) {
    const float dist = sqrtf(sd[0] + sd[1] + sd[2] + sd[3]);
    const int m = mask[row];
    const int newly = (dist < EPS_CONV) ? 1 : 0;
    if (!m && newly) mask[row] = 1;
    frozen_sh = m | newly;
  }
  __syncthreads();
  if (!frozen_sh) {
    float2* zp = (float2*)(z + (size_t)row * D_DIM);
    float2 zv = zp[t];
    zv.x += d.x; zv.y += d.y;
    zp[t] = zv;
  }
}

template <int BM, int BN>
__global__ __launch_bounds__(256)
void gemm_fp32_fallback(const float* __restrict__ A, const float* __restrict__ W,
                        const float* __restrict__ bias, float* __restrict__ C,
                        int M, int N, int K, int do_gelu) {
  constexpr int BK = 8;
  constexpr int TM = BM / 16;
  constexpr int TN = BN / 16;
  __shared__ float As[BK][BM];
  __shared__ float Bs[BK][BN];
  const int tid = threadIdx.x;
  const int m0 = blockIdx.x * BM;
  const int n0 = blockIdx.y * BN;
  const int ty = tid >> 4, tx = tid & 15;
  float acc[TM][TN];
#pragma unroll
  for (int i = 0; i < TM; ++i)
#pragma unroll
    for (int j = 0; j < TN; ++j) acc[i][j] = 0.0f;
  for (int k0 = 0; k0 < K; k0 += BK) {
    if constexpr (BM == 128) {
      const int row = tid >> 1, col = (tid & 1) * 4;
      const float4 a = *(const float4*)(A + (size_t)(m0 + row) * K + k0 + col);
      As[col + 0][row] = a.x; As[col + 1][row] = a.y;
      As[col + 2][row] = a.z; As[col + 3][row] = a.w;
    } else {
      const int row = tid >> 2, col = (tid & 3) * 2;
      const float2 a = *(const float2*)(A + (size_t)(m0 + row) * K + k0 + col);
      As[col + 0][row] = a.x; As[col + 1][row] = a.y;
    }
    {
      const int row = tid >> 5, col = (tid & 31) * 4;
      const float4 w = *(const float4*)(W + (size_t)(k0 + row) * N + n0 + col);
      *(float4*)(&Bs[row][col]) = w;
    }
    __syncthreads();
#pragma unroll
    for (int kk = 0; kk < BK; ++kk) {
      float a[TM], b[TN];
#pragma unroll
      for (int i = 0; i < TM; i += 4)
        *(float4*)(a + i) = *(const float4*)(&As[kk][ty * TM + i]);
#pragma unroll
      for (int j = 0; j < TN; j += 4)
        *(float4*)(b + j) = *(const float4*)(&Bs[kk][tx * TN + j]);
#pragma unroll
      for (int i = 0; i < TM; ++i)
#pragma unroll
        for (int j = 0; j < TN; ++j) acc[i][j] = fmaf(a[i], b[j], acc[i][j]);
    }
    __syncthreads();
  }
  float bv[TN];
#pragma unroll
  for (int j = 0; j < TN; ++j) bv[j] = bias[n0 + tx * TN + j];
#pragma unroll
  for (int i = 0; i < TM; ++i) {
    const int r = m0 + ty * TM + i;
#pragma unroll
    for (int j = 0; j < TN; j += 4) {
      float4 v;
      v.x = acc[i][j + 0] + bv[j + 0]; v.y = acc[i][j + 1] + bv[j + 1];
      v.z = acc[i][j + 2] + bv[j + 2]; v.w = acc[i][j + 3] + bv[j + 3];
      if (do_gelu) {
        v.x = gelu_exact(v.x); v.y = gelu_exact(v.y);
        v.z = gelu_exact(v.z); v.w = gelu_exact(v.w);
      }
      *(float4*)(C + (size_t)r * N + n0 + tx * TN + j) = v;
    }
  }
}

// ============ launch =======================================================
extern "C" void kernel_launch(void* const* d_in, const int* in_sizes, int n_in,
                              void* d_out, int out_size, void* d_ws,
                              size_t ws_size, hipStream_t stream) {
  const float* z_init = (const float*)d_in[0];
  const float* ln1_g  = (const float*)d_in[1];
  const float* ln1_b  = (const float*)d_in[2];
  const float* w1     = (const float*)d_in[3];
  const float* b1     = (const float*)d_in[4];
  const float* w2     = (const float*)d_in[5];
  const float* b2     = (const float*)d_in[6];
  const float* ln2_g  = (const float*)d_in[7];
  const float* ln2_b  = (const float*)d_in[8];
  const float* w3     = (const float*)d_in[9];
  const float* b3     = (const float*)d_in[10];
  const float* w4     = (const float*)d_in[11];
  const float* b4     = (const float*)d_in[12];
  const float* clf_w  = (const float*)d_in[13];
  const float* clf_b  = (const float*)d_in[14];

  float* out    = (float*)d_out;
  float* logits = out;
  float* maskf  = out + B_ROWS;
  float* z      = out + 2 * B_ROWS;   // [B,D] in d_out

  const size_t BD = (size_t)B_ROWS * D_DIM;
  const size_t BH = (size_t)B_ROWS * H_DIM;
  const size_t WSZ = (size_t)D_DIM * H_DIM;

  // layout: xp | hp | y | w1p..w4p | mask | p1
  uint32* xp  = (uint32*)d_ws;           // [B,D] packed tiled
  uint32* hp  = xp + BD;                 // [B,H] packed tiled
  float*  y   = (float*)(hp + BH);       // [B,D] fp32 split-K chunk 0
  uint32* w1p = (uint32*)(y + BD);       // each WSZ u32, packed tiled [N][K]
  uint32* w2p = w1p + WSZ;
  uint32* w3p = w2p + WSZ;
  uint32* w4p = w3p + WSZ;
  int*    mask = (int*)(w4p + WSZ);
  float*  p1  = (float*)(mask + B_ROWS); // [B,D] fp32 split-K chunk 1
  const size_t need = (uintptr_t)((char*)(p1 + BD) - (char*)d_ws) + 256;

  init_kernel<<<(int)((BD + 255) / 256), 256, 0, stream>>>(z_init, z, mask,
                                                           (int)BD);

  if (ws_size >= need) {
    const dim3 tb(32, 8);
    transpose_split_kernel<<<dim3(H_DIM / 32, D_DIM / 32), tb, 0, stream>>>(w1, w1p, D_DIM, H_DIM);
    transpose_split_kernel<<<dim3(D_DIM / 32, H_DIM / 32), tb, 0, stream>>>(w2, w2p, H_DIM, D_DIM);
    transpose_split_kernel<<<dim3(H_DIM / 32, D_DIM / 32), tb, 0, stream>>>(w3, w3p, D_DIM, H_DIM);
    transpose_split_kernel<<<dim3(D_DIM / 32, H_DIM / 32), tb, 0, stream>>>(w4, w4p, H_DIM, D_DIM);

    const dim3 g_up(B_ROWS / 128, H_DIM / 128, 1);   // 512 blocks
    const dim3 g_dn(B_ROWS / 128, D_DIM / 64, 2);    // 512 blocks, split-K=2
    for (int s = 0; s < N_STEPS; ++s) {
      ln_pack_kernel<<<B_ROWS, 256, 0, stream>>>(z, nullptr, ln1_g, ln1_b, xp);
      gemm_direct<128, true><<<g_up, 256, 0, stream>>>(
          xp, w1p, b1, hp, nullptr, nullptr, B_ROWS, H_DIM, D_DIM, D_DIM);
      gemm_direct<64, false><<<g_dn, 256, 0, stream>>>(
          hp, w2p, b2, nullptr, y, p1, B_ROWS, D_DIM, H_DIM, H_DIM / 2);
      ln_pack_kernel<<<B_ROWS, 256, 0, stream>>>(y, p1, ln2_g, ln2_b, xp);
      gemm_direct<128, true><<<g_up, 256, 0, stream>>>(
          xp, w3p, b3, hp, nullptr, nullptr, B_ROWS, H_DIM, D_DIM, D_DIM);
      gemm_direct<64, false><<<g_dn, 256, 0, stream>>>(
          hp, w4p, b4, nullptr, y, p1, B_ROWS, D_DIM, H_DIM, H_DIM / 2);
      update_kernel<<<B_ROWS, 256, 0, stream>>>(z, y, p1, mask);
    }
  } else {
    // fallback: fp32 pipeline
    float* x  = (float*)d_ws;
    float* yf = x + BD;
    float* h  = yf + BD;
    int* mask_fb = (int*)(h + BH);
    mask = mask_fb;
    const dim3 g_up(B_ROWS / 128, H_DIM / 128);
    const dim3 g_dn(B_ROWS / 64, D_DIM / 128);
    for (int s = 0; s < N_STEPS; ++s) {
      ln_f32_kernel<<<B_ROWS, 256, 0, stream>>>(z, ln1_g, ln1_b, x);
      gemm_fp32_fallback<128, 128><<<g_up, 256, 0, stream>>>(x, w1, b1, h, B_ROWS, H_DIM, D_DIM, 1);
      gemm_fp32_fallback<64, 128><<<g_dn, 256, 0, stream>>>(h, w2, b2, yf, B_ROWS, D_DIM, H_DIM, 0);
      ln_f32_kernel<<<B_ROWS, 256, 0, stream>>>(yf, ln2_g, ln2_b, x);
      gemm_fp32_fallback<128, 128><<<g_up, 256, 0, stream>>>(x, w3, b3, h, B_ROWS, H_DIM, D_DIM, 1);
      gemm_fp32_fallback<64, 128><<<g_dn, 256, 0, stream>>>(h, w4, b4, yf, B_ROWS, D_DIM, H_DIM, 0);
      update_f32_kernel<<<B_ROWS, 256, 0, stream>>>(z, yf, mask);
    }
  }
  final_kernel<<<B_ROWS, 256, 0, stream>>>(z, clf_w, clf_b, mask, logits, maskf);
}

// Round 6
// 6207.397 us; speedup vs baseline: 1.7518x; 1.0417x over previous
//
#include <hip/hip_runtime.h>

#define B_ROWS  4096
#define D_DIM   512
#define H_DIM   2048
#define N_STEPS 32
#define EPS_CONV 0.01f
#define LN_EPSF  1e-5f

typedef __attribute__((ext_vector_type(4))) float f32x4;
typedef __attribute__((ext_vector_type(8))) _Float16 h16x8;
typedef unsigned short ushort_t;
typedef unsigned int uint32;

__device__ __forceinline__ float wave_reduce_sum(float v) {
#pragma unroll
  for (int o = 32; o > 0; o >>= 1) v += __shfl_down(v, o, 64);
  return v;
}

__device__ __forceinline__ float gelu_exact(float v) {
  return 0.5f * v * (1.0f + erff(v * 0.7071067811865476f));
}

__device__ __forceinline__ ushort_t h_bits(_Float16 h) {
  union { _Float16 f; ushort_t u; } c; c.f = h; return c.u;
}

// Fragment-plane tiling (ushort units). Tile = 16 rows x 32 k:
//   1KB hi plane (512 halves) then 1KB lo plane.
//   lane = ((k>>3)&3)*16 + (row&15)  (MFMA lane q*16+l16), in-lane idx k&7.
//   hi at tile*1024 + lane*8 + (k&7); lo at +512.
// A wave's fragment load = ONE fully lane-coalesced 1KB dwordx4 per plane.
__device__ __forceinline__ size_t amap_h(int row, int k, int K) {
  return ((size_t)((row >> 4) * (K >> 5) + (k >> 5)) << 10) +
         ((((((k >> 3) & 3) << 4) + (row & 15))) << 3) + (k & 7);
}

// ============ LayerNorm -> separate hi/lo f16 planes, fragment-tiled =======
__global__ __launch_bounds__(256)
void ln_pack_kernel(const float* in, const float* in2, const float* g,
                    const float* b, ushort_t* outp) {
  const int row = blockIdx.x;
  const int t = threadIdx.x;
  float2 v = ((const float2*)(in + (size_t)row * D_DIM))[t];
  if (in2 != nullptr) {
    const float2 w = ((const float2*)(in2 + (size_t)row * D_DIM))[t];
    v.x += w.x; v.y += w.y;
  }
  float s  = v.x + v.y;
  float sq = v.x * v.x + v.y * v.y;
  s  = wave_reduce_sum(s);
  sq = wave_reduce_sum(sq);
  __shared__ float sd1[4], sd2[4], mb[2];
  const int lane = t & 63, wid = t >> 6;
  if (lane == 0) { sd1[wid] = s; sd2[wid] = sq; }
  __syncthreads();
  if (t == 0) {
    float st = sd1[0] + sd1[1] + sd1[2] + sd1[3];
    float qt = sd2[0] + sd2[1] + sd2[2] + sd2[3];
    float mean = st * (1.0f / (float)D_DIM);
    float var  = qt * (1.0f / (float)D_DIM) - mean * mean;
    mb[0] = mean;
    mb[1] = rsqrtf(var + LN_EPSF);
  }
  __syncthreads();
  const float mean = mb[0], rstd = mb[1];
  const float2 gv = ((const float2*)g)[t];
  const float2 bv = ((const float2*)b)[t];
  const float r0 = (v.x - mean) * rstd * gv.x + bv.x;
  const float r1 = (v.y - mean) * rstd * gv.y + bv.y;
  const _Float16 h0 = (_Float16)r0, h1 = (_Float16)r1;
  const _Float16 l0 = (_Float16)((r0 - (float)h0) * 1024.0f);
  const _Float16 l1 = (_Float16)((r1 - (float)h1) * 1024.0f);
  const size_t base = amap_h(row, 2 * t, D_DIM);   // k=2t,2t+1 adjacent
  union { _Float16 f[2]; uint32 u; } ph, pl;
  ph.f[0] = h0; ph.f[1] = h1;
  pl.f[0] = l0; pl.f[1] = l1;
  *(uint32*)(outp + base) = ph.u;
  *(uint32*)(outp + base + 512) = pl.u;
}

// ============ weight transpose + split into hi/lo planes (one-time) ========
__global__ __launch_bounds__(256)
void transpose_split_kernel(const float* __restrict__ w,
                            ushort_t* __restrict__ wp, int K, int N) {
  __shared__ float t[32][33];
  const int tx = threadIdx.x;   // 0..31
  const int ty = threadIdx.y;   // 0..7
  const int n_base = blockIdx.x * 32;
  const int k_base = blockIdx.y * 32;
#pragma unroll
  for (int r = 0; r < 4; ++r)
    t[ty + r * 8][tx] = w[(size_t)(k_base + ty + r * 8) * N + n_base + tx];
  __syncthreads();
#pragma unroll
  for (int r = 0; r < 4; ++r) {
    const int n = n_base + ty + r * 8;
    const int k = k_base + tx;
    const float v = t[tx][ty + r * 8];
    const _Float16 hi = (_Float16)v;
    const _Float16 lo = (_Float16)((v - (float)hi) * 1024.0f);
    const size_t base = amap_h(n, k, K);
    wp[base] = h_bits(hi);
    wp[base + 512] = h_bits(lo);
  }
}

// ============ zero-LDS, zero-perm, 2-deep-pipelined f16x3 MFMA GEMM ========
// A, W: f16 hi/lo fragment planes. BM=128, BN=64, BK=32, 4 waves 2x2.
// OUT_PACK: C -> gelu, split to hi/lo planes (next GEMM's A). else: fp32
// partial to C0 (z==0, +bias) / C1 (z==1), row-major.
template <bool OUT_PACK>
__global__ __launch_bounds__(256, 2)
void gemm_direct(const ushort_t* __restrict__ Ah, const ushort_t* __restrict__ Wh,
                 const float* __restrict__ bias, ushort_t* __restrict__ Cp,
                 float* __restrict__ C0, float* __restrict__ C1,
                 int M, int N, int K, int kc) {
  const int KT = K >> 5;           // k-tiles total
  const int NKT = kc >> 5;         // k-tiles this block (even, >= 4)

  const int tid = threadIdx.x;
  const int lane = tid & 63;
  const int wid = tid >> 6;
  const int q = lane >> 4;
  const int l16 = lane & 15;
  const int wm = wid >> 1;
  const int wn = wid & 1;

  const int m0 = blockIdx.x * 128;
  const int n0 = blockIdx.y * 64;
  const int kt0 = blockIdx.z * NKT;

  const ushort_t* pa[4];
#pragma unroll
  for (int i = 0; i < 4; ++i) {
    const int tm = (m0 >> 4) + wm * 4 + i;
    pa[i] = Ah + ((size_t)(tm * KT + kt0) << 10) + lane * 8;
  }
  const ushort_t* pb[2];
#pragma unroll
  for (int j = 0; j < 2; ++j) {
    const int tn = (n0 >> 4) + wn * 2 + j;
    pb[j] = Wh + ((size_t)(tn * KT + kt0) << 10) + lane * 8;
  }

  f32x4 acc_h[4][2], acc_m[4][2];
#pragma unroll
  for (int i = 0; i < 4; ++i)
#pragma unroll
    for (int j = 0; j < 2; ++j) {
      acc_h[i][j] = (f32x4){0.f, 0.f, 0.f, 0.f};
      acc_m[i][j] = (f32x4){0.f, 0.f, 0.f, 0.f};
    }

  h16x8 a0h[4], a0l[4], a1h[4], a1l[4];
  h16x8 b0h[2], b0l[2], b1h[2], b1l[2];

#define LDF(p, off) (*(const h16x8*)((p) + (off)))
#define MFMA_BANK(AH, AL, BH, BL)                                             \
  _Pragma("unroll") for (int i = 0; i < 4; ++i)                               \
  _Pragma("unroll") for (int j = 0; j < 2; ++j) {                             \
    acc_h[i][j] = __builtin_amdgcn_mfma_f32_16x16x32_f16(AH[i], BH[j],        \
                                                         acc_h[i][j], 0, 0, 0);\
    acc_m[i][j] = __builtin_amdgcn_mfma_f32_16x16x32_f16(AL[i], BH[j],        \
                                                         acc_m[i][j], 0, 0, 0);\
    acc_m[i][j] = __builtin_amdgcn_mfma_f32_16x16x32_f16(AH[i], BL[j],        \
                                                         acc_m[i][j], 0, 0, 0);\
  }

  // preload bank0 (k-tile 0)
#pragma unroll
  for (int i = 0; i < 4; ++i) { a0h[i] = LDF(pa[i], 0); a0l[i] = LDF(pa[i], 512); }
#pragma unroll
  for (int j = 0; j < 2; ++j) { b0h[j] = LDF(pb[j], 0); b0l[j] = LDF(pb[j], 512); }

  for (int kt = 0; kt < NKT - 2; kt += 2) {
    // load bank1 (kt+1) at +1024/+1536 (same 4KB imm window)
#pragma unroll
    for (int i = 0; i < 4; ++i) { a1h[i] = LDF(pa[i], 1024); a1l[i] = LDF(pa[i], 1536); }
#pragma unroll
    for (int j = 0; j < 2; ++j) { b1h[j] = LDF(pb[j], 1024); b1l[j] = LDF(pb[j], 1536); }
    MFMA_BANK(a0h, a0l, b0h, b0l)
#pragma unroll
    for (int i = 0; i < 4; ++i) pa[i] += 2048;
#pragma unroll
    for (int j = 0; j < 2; ++j) pb[j] += 2048;
    // load bank0 (kt+2)
#pragma unroll
    for (int i = 0; i < 4; ++i) { a0h[i] = LDF(pa[i], 0); a0l[i] = LDF(pa[i], 512); }
#pragma unroll
    for (int j = 0; j < 2; ++j) { b0h[j] = LDF(pb[j], 0); b0l[j] = LDF(pb[j], 512); }
    MFMA_BANK(a1h, a1l, b1h, b1l)
  }
  // final pair
#pragma unroll
  for (int i = 0; i < 4; ++i) { a1h[i] = LDF(pa[i], 1024); a1l[i] = LDF(pa[i], 1536); }
#pragma unroll
  for (int j = 0; j < 2; ++j) { b1h[j] = LDF(pb[j], 1024); b1l[j] = LDF(pb[j], 1536); }
  MFMA_BANK(a0h, a0l, b0h, b0l)
  MFMA_BANK(a1h, a1l, b1h, b1l)
#undef MFMA_BANK
#undef LDF

  // ---- epilogue ----
#pragma unroll
  for (int i = 0; i < 4; ++i) {
    const int row = m0 + wm * 64 + i * 16 + q * 4;
#pragma unroll
    for (int j = 0; j < 2; ++j) {
      const int col = n0 + wn * 32 + j * 16 + l16;
      if (OUT_PACK) {
        const float bv = bias[col];
#pragma unroll
        for (int r = 0; r < 4; ++r) {
          const float v = gelu_exact(acc_h[i][j][r] +
                                     acc_m[i][j][r] * (1.0f / 1024.0f) + bv);
          const _Float16 hi = (_Float16)v;
          const _Float16 lo = (_Float16)((v - (float)hi) * 1024.0f);
          const size_t base = amap_h(row + r, col, N);
          Cp[base] = h_bits(hi);
          Cp[base + 512] = h_bits(lo);
        }
      } else {
        float* C = (blockIdx.z == 0) ? C0 : C1;
        const float bv = (blockIdx.z == 0) ? bias[col] : 0.0f;
#pragma unroll
        for (int r = 0; r < 4; ++r) {
          C[(size_t)(row + r) * N + col] =
              acc_h[i][j][r] + acc_m[i][j][r] * (1.0f / 1024.0f) + bv;
        }
      }
    }
  }
}

// ============ update: z += (d0+d1) unless converged ========================
__global__ __launch_bounds__(256)
void update_kernel(float* __restrict__ z, const float* __restrict__ d0,
                   const float* __restrict__ d1, int* __restrict__ mask) {
  const int row = blockIdx.x;
  const int t = threadIdx.x;
  float2 d = ((const float2*)(d0 + (size_t)row * D_DIM))[t];
  const float2 e = ((const float2*)(d1 + (size_t)row * D_DIM))[t];
  d.x += e.x; d.y += e.y;
  float sq = d.x * d.x + d.y * d.y;
  sq = wave_reduce_sum(sq);
  __shared__ float sd[4];
  __shared__ int frozen_sh;
  const int lane = t & 63, wid = t >> 6;
  if (lane == 0) sd[wid] = sq;
  __syncthreads();
  if (t == 0) {
    const float dist = sqrtf(sd[0] + sd[1] + sd[2] + sd[3]);
    const int m = mask[row];
    const int newly = (dist < EPS_CONV) ? 1 : 0;
    if (!m && newly) mask[row] = 1;
    frozen_sh = m | newly;
  }
  __syncthreads();
  if (!frozen_sh) {
    float2* zp = (float2*)(z + (size_t)row * D_DIM);
    float2 zv = zp[t];
    zv.x += d.x; zv.y += d.y;
    zp[t] = zv;
  }
}

__global__ __launch_bounds__(256)
void final_kernel(const float* __restrict__ z, const float* __restrict__ clf_w,
                  const float* __restrict__ clf_b, const int* __restrict__ mask,
                  float* __restrict__ logits, float* __restrict__ maskf) {
  const int row = blockIdx.x;
  const int t = threadIdx.x;
  const float2 zv = ((const float2*)(z + (size_t)row * D_DIM))[t];
  const float2 wv = ((const float2*)clf_w)[t];
  float s = zv.x * wv.x + zv.y * wv.y;
  s = wave_reduce_sum(s);
  __shared__ float sd[4];
  const int lane = t & 63, wid = t >> 6;
  if (lane == 0) sd[wid] = s;
  __syncthreads();
  if (t == 0) {
    logits[row] = sd[0] + sd[1] + sd[2] + sd[3] + clf_b[0];
    maskf[row] = mask[row] ? 1.0f : 0.0f;
  }
}

__global__ void init_kernel(const float* __restrict__ z_init,
                            float* __restrict__ z, int* __restrict__ mask,
                            int n) {
  const int i = blockIdx.x * blockDim.x + threadIdx.x;
  if (i < n) z[i] = z_init[i];
  if (i < B_ROWS) mask[i] = 0;
}

// ============ fp32 fallback (only if ws too small) =========================
__global__ __launch_bounds__(256)
void ln_f32_kernel(const float* __restrict__ in, const float* __restrict__ g,
                   const float* __restrict__ b, float* __restrict__ out) {
  const int row = blockIdx.x;
  const int t = threadIdx.x;
  const float2 v = ((const float2*)(in + (size_t)row * D_DIM))[t];
  float s = v.x + v.y, sq = v.x * v.x + v.y * v.y;
  s = wave_reduce_sum(s); sq = wave_reduce_sum(sq);
  __shared__ float sd1[4], sd2[4], mb[2];
  const int lane = t & 63, wid = t >> 6;
  if (lane == 0) { sd1[wid] = s; sd2[wid] = sq; }
  __syncthreads();
  if (t == 0) {
    float st = sd1[0] + sd1[1] + sd1[2] + sd1[3];
    float qt = sd2[0] + sd2[1] + sd2[2] + sd2[3];
    float mean = st / (float)D_DIM;
    float var = qt / (float)D_DIM - mean * mean;
    mb[0] = mean; mb[1] = rsqrtf(var + LN_EPSF);
  }
  __syncthreads();
  const float mean = mb[0], rstd = mb[1];
  const float2 gv = ((const float2*)g)[t];
  const float2 bv = ((const float2*)b)[t];
  float2 r;
  r.x = (v.x - mean) * rstd * gv.x + bv.x;
  r.y = (v.y - mean) * rstd * gv.y + bv.y;
  ((float2*)(out + (size_t)row * D_DIM))[t] = r;
}

__global__ __launch_bounds__(256)
void update_f32_kernel(float* __restrict__ z, const float* __restrict__ delta,
                       int* __restrict__ mask) {
  const int row = blockIdx.x;
  const int t = threadIdx.x;
  const float2 d = ((const float2*)(delta + (size_t)row * D_DIM))[t];
  float sq = d.x * d.x + d.y * d.y;
  sq = wave_reduce_sum(sq);
  __shared__ float sd[4];
  __shared__ int frozen_sh;
  const int lane = t & 63, wid = t >> 6;
  if (lane == 0) sd[wid] = sq;
  __syncthreads();
  if (t == 0) {
    const float dist = sqrtf(sd[0] + sd[1] + sd[2] + sd[3]);
    const int m = mask[row];
    const int newly = (dist < EPS_CONV) ? 1 : 0;
    if (!m && newly) mask[row] = 1;
    frozen_sh = m | newly;
  }
  __syncthreads();
  if (!frozen_sh) {
    float2* zp = (float2*)(z + (size_t)row * D_DIM);
    float2 zv = zp[t];
    zv.x += d.x; zv.y += d.y;
    zp[t] = zv;
  }
}

template <int BM, int BN>
__global__ __launch_bounds__(256)
void gemm_fp32_fallback(const float* __restrict__ A, const float* __restrict__ W,
                        const float* __restrict__ bias, float* __restrict__ C,
                        int M, int N, int K, int do_gelu) {
  constexpr int BK = 8;
  constexpr int TM = BM / 16;
  constexpr int TN = BN / 16;
  __shared__ float As[BK][BM];
  __shared__ float Bs[BK][BN];
  const int tid = threadIdx.x;
  const int m0 = blockIdx.x * BM;
  const int n0 = blockIdx.y * BN;
  const int ty = tid >> 4, tx = tid & 15;
  float acc[TM][TN];
#pragma unroll
  for (int i = 0; i < TM; ++i)
#pragma unroll
    for (int j = 0; j < TN; ++j) acc[i][j] = 0.0f;
  for (int k0 = 0; k0 < K; k0 += BK) {
    if constexpr (BM == 128) {
      const int row = tid >> 1, col = (tid & 1) * 4;
      const float4 a = *(const float4*)(A + (size_t)(m0 + row) * K + k0 + col);
      As[col + 0][row] = a.x; As[col + 1][row] = a.y;
      As[col + 2][row] = a.z; As[col + 3][row] = a.w;
    } else {
      const int row = tid >> 2, col = (tid & 3) * 2;
      const float2 a = *(const float2*)(A + (size_t)(m0 + row) * K + k0 + col);
      As[col + 0][row] = a.x; As[col + 1][row] = a.y;
    }
    {
      const int row = tid >> 5, col = (tid & 31) * 4;
      const float4 w = *(const float4*)(W + (size_t)(k0 + row) * N + n0 + col);
      *(float4*)(&Bs[row][col]) = w;
    }
    __syncthreads();
#pragma unroll
    for (int kk = 0; kk < BK; ++kk) {
      float a[TM], b[TN];
#pragma unroll
      for (int i = 0; i < TM; i += 4)
        *(float4*)(a + i) = *(const float4*)(&As[kk][ty * TM + i]);
#pragma unroll
      for (int j = 0; j < TN; j += 4)
        *(float4*)(b + j) = *(const float4*)(&Bs[kk][tx * TN + j]);
#pragma unroll
      for (int i = 0; i < TM; ++i)
#pragma unroll
        for (int j = 0; j < TN; ++j) acc[i][j] = fmaf(a[i], b[j], acc[i][j]);
    }
    __syncthreads();
  }
  float bv[TN];
#pragma unroll
  for (int j = 0; j < TN; ++j) bv[j] = bias[n0 + tx * TN + j];
#pragma unroll
  for (int i = 0; i < TM; ++i) {
    const int r = m0 + ty * TM + i;
#pragma unroll
    for (int j = 0; j < TN; j += 4) {
      float4 v;
      v.x = acc[i][j + 0] + bv[j + 0]; v.y = acc[i][j + 1] + bv[j + 1];
      v.z = acc[i][j + 2] + bv[j + 2]; v.w = acc[i][j + 3] + bv[j + 3];
      if (do_gelu) {
        v.x = gelu_exact(v.x); v.y = gelu_exact(v.y);
        v.z = gelu_exact(v.z); v.w = gelu_exact(v.w);
      }
      *(float4*)(C + (size_t)r * N + n0 + tx * TN + j) = v;
    }
  }
}

// ============ launch =======================================================
extern "C" void kernel_launch(void* const* d_in, const int* in_sizes, int n_in,
                              void* d_out, int out_size, void* d_ws,
                              size_t ws_size, hipStream_t stream) {
  const float* z_init = (const float*)d_in[0];
  const float* ln1_g  = (const float*)d_in[1];
  const float* ln1_b  = (const float*)d_in[2];
  const float* w1     = (const float*)d_in[3];
  const float* b1     = (const float*)d_in[4];
  const float* w2     = (const float*)d_in[5];
  const float* b2     = (const float*)d_in[6];
  const float* ln2_g  = (const float*)d_in[7];
  const float* ln2_b  = (const float*)d_in[8];
  const float* w3     = (const float*)d_in[9];
  const float* b3     = (const float*)d_in[10];
  const float* w4     = (const float*)d_in[11];
  const float* b4     = (const float*)d_in[12];
  const float* clf_w  = (const float*)d_in[13];
  const float* clf_b  = (const float*)d_in[14];

  float* out    = (float*)d_out;
  float* logits = out;
  float* maskf  = out + B_ROWS;
  float* z      = out + 2 * B_ROWS;   // [B,D] in d_out

  const size_t BD = (size_t)B_ROWS * D_DIM;
  const size_t BH = (size_t)B_ROWS * H_DIM;
  const size_t WSZ = (size_t)D_DIM * H_DIM;

  // layout (ushort planes hold 2 halves per element):
  ushort_t* xh  = (ushort_t*)d_ws;        // [B,D] hi/lo planes: BD*2 ushorts
  ushort_t* hp  = xh + BD * 2;            // [B,H] hi/lo planes: BH*2 ushorts
  float*    y   = (float*)(hp + BH * 2);  // [B,D] fp32 split-K chunk 0
  float*    p1  = y + BD;                 // [B,D] fp32 split-K chunk 1
  ushort_t* w1p = (ushort_t*)(p1 + BD);   // each WSZ*2 ushorts
  ushort_t* w2p = w1p + WSZ * 2;
  ushort_t* w3p = w2p + WSZ * 2;
  ushort_t* w4p = w3p + WSZ * 2;
  int*     mask = (int*)(w4p + WSZ * 2);
  const size_t need = (uintptr_t)((char*)(mask + B_ROWS) - (char*)d_ws) + 256;

  init_kernel<<<(int)((BD + 255) / 256), 256, 0, stream>>>(z_init, z, mask,
                                                           (int)BD);

  if (ws_size >= need) {
    const dim3 tb(32, 8);
    transpose_split_kernel<<<dim3(H_DIM / 32, D_DIM / 32), tb, 0, stream>>>(w1, w1p, D_DIM, H_DIM);
    transpose_split_kernel<<<dim3(D_DIM / 32, H_DIM / 32), tb, 0, stream>>>(w2, w2p, H_DIM, D_DIM);
    transpose_split_kernel<<<dim3(H_DIM / 32, D_DIM / 32), tb, 0, stream>>>(w3, w3p, D_DIM, H_DIM);
    transpose_split_kernel<<<dim3(D_DIM / 32, H_DIM / 32), tb, 0, stream>>>(w4, w4p, H_DIM, D_DIM);

    const dim3 g_up(B_ROWS / 128, H_DIM / 64, 1);    // 32x32 = 1024 blocks
    const dim3 g_dn(B_ROWS / 128, D_DIM / 64, 2);    // 32x8x2 = 512 blocks
    for (int s = 0; s < N_STEPS; ++s) {
      ln_pack_kernel<<<B_ROWS, 256, 0, stream>>>(z, nullptr, ln1_g, ln1_b, xh);
      gemm_direct<true><<<g_up, 256, 0, stream>>>(
          xh, w1p, b1, hp, nullptr, nullptr, B_ROWS, H_DIM, D_DIM, D_DIM);
      gemm_direct<false><<<g_dn, 256, 0, stream>>>(
          hp, w2p, b2, nullptr, y, p1, B_ROWS, D_DIM, H_DIM, H_DIM / 2);
      ln_pack_kernel<<<B_ROWS, 256, 0, stream>>>(y, p1, ln2_g, ln2_b, xh);
      gemm_direct<true><<<g_up, 256, 0, stream>>>(
          xh, w3p, b3, hp, nullptr, nullptr, B_ROWS, H_DIM, D_DIM, D_DIM);
      gemm_direct<false><<<g_dn, 256, 0, stream>>>(
          hp, w4p, b4, nullptr, y, p1, B_ROWS, D_DIM, H_DIM, H_DIM / 2);
      update_kernel<<<B_ROWS, 256, 0, stream>>>(z, y, p1, mask);
    }
  } else {
    // fallback: fp32 pipeline
    float* x  = (float*)d_ws;
    float* yf = x + BD;
    float* h  = yf + BD;
    int* mask_fb = (int*)(h + BH);
    mask = mask_fb;
    const dim3 g_up(B_ROWS / 128, H_DIM / 128);
    const dim3 g_dn(B_ROWS / 64, D_DIM / 128);
    for (int s = 0; s < N_STEPS; ++s) {
      ln_f32_kernel<<<B_ROWS, 256, 0, stream>>>(z, ln1_g, ln1_b, x);
      gemm_fp32_fallback<128, 128><<<g_up, 256, 0, stream>>>(x, w1, b1, h, B_ROWS, H_DIM, D_DIM, 1);
      gemm_fp32_fallback<64, 128><<<g_dn, 256, 0, stream>>>(h, w2, b2, yf, B_ROWS, D_DIM, H_DIM, 0);
      ln_f32_kernel<<<B_ROWS, 256, 0, stream>>>(yf, ln2_g, ln2_b, x);
      gemm_fp32_fallback<128, 128><<<g_up, 256, 0, stream>>>(x, w3, b3, h, B_ROWS, H_DIM, D_DIM, 1);
      gemm_fp32_fallback<64, 128><<<g_dn, 256, 0, stream>>>(h, w4, b4, yf, B_ROWS, D_DIM, H_DIM, 0);
      update_f32_kernel<<<B_ROWS, 256, 0, stream>>>(z, yf, mask);
    }
  }
  final_kernel<<<B_ROWS, 256, 0, stream>>>(z, clf_w, clf_b, mask, logits, maskf);
}

// Round 8
// 5997.783 us; speedup vs baseline: 1.8130x; 1.0349x over previous
//
#include <hip/hip_runtime.h>

#define B_ROWS  4096
#define D_DIM   512
#define H_DIM   2048
#define N_STEPS 32
#define EPS_CONV 0.01f
#define LN_EPSF  1e-5f

typedef __attribute__((ext_vector_type(16))) float f32x16;
typedef __attribute__((ext_vector_type(8))) _Float16 h16x8;
typedef unsigned short ushort_t;
typedef unsigned int uint32;

__device__ __forceinline__ float wave_reduce_sum(float v) {
#pragma unroll
  for (int o = 32; o > 0; o >>= 1) v += __shfl_down(v, o, 64);
  return v;
}

__device__ __forceinline__ float gelu_exact(float v) {
  return 0.5f * v * (1.0f + erff(v * 0.7071067811865476f));
}

__device__ __forceinline__ ushort_t h_bits(_Float16 h) {
  union { _Float16 f; ushort_t u; } c; c.f = h; return c.u;
}

// 32x32x16-MFMA fragment-plane tiling (ushort units).
// Tile = 32 rows x 16 k: 512-half hi plane + 512-half lo plane (1024/tile).
//   lane = ((k>>3)&1)*32 + (row&31)   (matches mfma_32x32x16 operand map)
//   in-lane idx = k&7;  hi at tile*1024 + lane*8 + (k&7), lo at +512.
// A wave's fragment load = ONE lane-coalesced 1KB dwordx4 per plane.
__device__ __forceinline__ size_t amap32(int row, int k, int K) {
  return ((size_t)((row >> 5) * (K >> 4) + (k >> 4)) << 10) +
         ((size_t)((((k >> 3) & 1) << 5) | (row & 31)) << 3) + (k & 7);
}

// ============ LayerNorm (sum of up to 4 inputs) -> hi/lo planes ============
__global__ __launch_bounds__(256)
void ln_pack_kernel(const float* in0, const float* in1, const float* in2,
                    const float* in3, const float* g, const float* b,
                    ushort_t* outp) {
  const int row = blockIdx.x;
  const int t = threadIdx.x;
  float2 v = ((const float2*)(in0 + (size_t)row * D_DIM))[t];
  if (in1) { const float2 w = ((const float2*)(in1 + (size_t)row * D_DIM))[t]; v.x += w.x; v.y += w.y; }
  if (in2) { const float2 w = ((const float2*)(in2 + (size_t)row * D_DIM))[t]; v.x += w.x; v.y += w.y; }
  if (in3) { const float2 w = ((const float2*)(in3 + (size_t)row * D_DIM))[t]; v.x += w.x; v.y += w.y; }
  float s  = v.x + v.y;
  float sq = v.x * v.x + v.y * v.y;
  s  = wave_reduce_sum(s);
  sq = wave_reduce_sum(sq);
  __shared__ float sd1[4], sd2[4], mb[2];
  const int lane = t & 63, wid = t >> 6;
  if (lane == 0) { sd1[wid] = s; sd2[wid] = sq; }
  __syncthreads();
  if (t == 0) {
    float st = sd1[0] + sd1[1] + sd1[2] + sd1[3];
    float qt = sd2[0] + sd2[1] + sd2[2] + sd2[3];
    float mean = st * (1.0f / (float)D_DIM);
    float var  = qt * (1.0f / (float)D_DIM) - mean * mean;
    mb[0] = mean;
    mb[1] = rsqrtf(var + LN_EPSF);
  }
  __syncthreads();
  const float mean = mb[0], rstd = mb[1];
  const float2 gv = ((const float2*)g)[t];
  const float2 bv = ((const float2*)b)[t];
  const float r0 = (v.x - mean) * rstd * gv.x + bv.x;
  const float r1 = (v.y - mean) * rstd * gv.y + bv.y;
  const _Float16 h0 = (_Float16)r0, h1 = (_Float16)r1;
  const _Float16 l0 = (_Float16)((r0 - (float)h0) * 1024.0f);
  const _Float16 l1 = (_Float16)((r1 - (float)h1) * 1024.0f);
  const size_t base = amap32(row, 2 * t, D_DIM);   // k=2t,2t+1 same lane slot
  union { _Float16 f[2]; uint32 u; } ph, pl;
  ph.f[0] = h0; ph.f[1] = h1;
  pl.f[0] = l0; pl.f[1] = l1;
  *(uint32*)(outp + base) = ph.u;
  *(uint32*)(outp + base + 512) = pl.u;
}

// ============ weight transpose + split into hi/lo planes (one-time) ========
__global__ __launch_bounds__(256)
void transpose_split_kernel(const float* __restrict__ w,
                            ushort_t* __restrict__ wp, int K, int N) {
  __shared__ float t[32][33];
  const int tx = threadIdx.x;   // 0..31
  const int ty = threadIdx.y;   // 0..7
  const int n_base = blockIdx.x * 32;
  const int k_base = blockIdx.y * 32;
#pragma unroll
  for (int r = 0; r < 4; ++r)
    t[ty + r * 8][tx] = w[(size_t)(k_base + ty + r * 8) * N + n_base + tx];
  __syncthreads();
#pragma unroll
  for (int r = 0; r < 4; ++r) {
    const int n = n_base + ty + r * 8;
    const int k = k_base + tx;
    const float v = t[tx][ty + r * 8];
    const _Float16 hi = (_Float16)v;
    const _Float16 lo = (_Float16)((v - (float)hi) * 1024.0f);
    const size_t base = amap32(n, k, K);
    wp[base] = h_bits(hi);
    wp[base + 512] = h_bits(lo);
  }
}

// ============ zero-LDS 32x32x16 f16x3 MFMA GEMM, wave tile 64x64 ===========
// A, W: f16 hi/lo fragment planes. Block 128x128, 4 waves 2x2, k-step 16.
// OUT_PACK: C -> gelu -> hi/lo planes (next GEMM's A). else: fp32 partial to
// Cz[blockIdx.z], bias added only on z==0.
template <bool OUT_PACK>
__global__ __launch_bounds__(256, 2)
void gemm32(const ushort_t* __restrict__ Ah, const ushort_t* __restrict__ Wh,
            const float* __restrict__ bias, ushort_t* __restrict__ Cp,
            float* __restrict__ C0, float* __restrict__ C1,
            float* __restrict__ C2, float* __restrict__ C3,
            int M, int N, int K, int kc) {
  const int KT = K >> 4;           // k-steps total (16 each)
  const int NKT = kc >> 4;         // k-steps this block (even, >= 4)

  const int tid = threadIdx.x;
  const int lane = tid & 63;
  const int wid = tid >> 6;
  const int wm = wid >> 1;
  const int wn = wid & 1;

  const int m0 = blockIdx.x * 128;
  const int n0 = blockIdx.y * 128;
  const int kz0 = blockIdx.z * NKT;   // in k-steps

  const ushort_t* pa[2];
#pragma unroll
  for (int i = 0; i < 2; ++i) {
    const int tm = (m0 >> 5) + wm * 2 + i;
    pa[i] = Ah + ((size_t)(tm * KT + kz0) << 10) + lane * 8;
  }
  const ushort_t* pb[2];
#pragma unroll
  for (int j = 0; j < 2; ++j) {
    const int tn = (n0 >> 5) + wn * 2 + j;
    pb[j] = Wh + ((size_t)(tn * KT + kz0) << 10) + lane * 8;
  }

  f32x16 acc_h[2][2], acc_m[2][2];
#pragma unroll
  for (int i = 0; i < 2; ++i)
#pragma unroll
    for (int j = 0; j < 2; ++j) {
      acc_h[i][j] = (f32x16)(0.0f);
      acc_m[i][j] = (f32x16)(0.0f);
    }

  h16x8 a0h[2], a0l[2], a1h[2], a1l[2];
  h16x8 b0h[2], b0l[2], b1h[2], b1l[2];

#define LDF(p, off) (*(const h16x8*)((p) + (off)))
#define MFMA_BANK(AH, AL, BH, BL)                                              \
  _Pragma("unroll") for (int i = 0; i < 2; ++i)                                \
  _Pragma("unroll") for (int j = 0; j < 2; ++j) {                              \
    acc_h[i][j] = __builtin_amdgcn_mfma_f32_32x32x16_f16(AH[i], BH[j],         \
                                                         acc_h[i][j], 0, 0, 0);\
    acc_m[i][j] = __builtin_amdgcn_mfma_f32_32x32x16_f16(AL[i], BH[j],         \
                                                         acc_m[i][j], 0, 0, 0);\
    acc_m[i][j] = __builtin_amdgcn_mfma_f32_32x32x16_f16(AH[i], BL[j],         \
                                                         acc_m[i][j], 0, 0, 0);\
  }

  // preload bank0 (k-step 0)
#pragma unroll
  for (int i = 0; i < 2; ++i) { a0h[i] = LDF(pa[i], 0); a0l[i] = LDF(pa[i], 512); }
#pragma unroll
  for (int j = 0; j < 2; ++j) { b0h[j] = LDF(pb[j], 0); b0l[j] = LDF(pb[j], 512); }

  for (int kt = 0; kt < NKT - 2; kt += 2) {
    // load bank1 (k-step kt+1) at +1024/+1536 halves (4KB imm window)
#pragma unroll
    for (int i = 0; i < 2; ++i) { a1h[i] = LDF(pa[i], 1024); a1l[i] = LDF(pa[i], 1536); }
#pragma unroll
    for (int j = 0; j < 2; ++j) { b1h[j] = LDF(pb[j], 1024); b1l[j] = LDF(pb[j], 1536); }
    MFMA_BANK(a0h, a0l, b0h, b0l)
#pragma unroll
    for (int i = 0; i < 2; ++i) pa[i] += 2048;
#pragma unroll
    for (int j = 0; j < 2; ++j) pb[j] += 2048;
    // load bank0 (k-step kt+2)
#pragma unroll
    for (int i = 0; i < 2; ++i) { a0h[i] = LDF(pa[i], 0); a0l[i] = LDF(pa[i], 512); }
#pragma unroll
    for (int j = 0; j < 2; ++j) { b0h[j] = LDF(pb[j], 0); b0l[j] = LDF(pb[j], 512); }
    MFMA_BANK(a1h, a1l, b1h, b1l)
  }
  // final pair
#pragma unroll
  for (int i = 0; i < 2; ++i) { a1h[i] = LDF(pa[i], 1024); a1l[i] = LDF(pa[i], 1536); }
#pragma unroll
  for (int j = 0; j < 2; ++j) { b1h[j] = LDF(pb[j], 1024); b1l[j] = LDF(pb[j], 1536); }
  MFMA_BANK(a0h, a0l, b0h, b0l)
  MFMA_BANK(a1h, a1l, b1h, b1l)
#undef MFMA_BANK
#undef LDF

  // ---- epilogue: C/D map col=lane&31, row=(r&3)+8*(r>>2)+4*(lane>>5) ----
  const int cq = (lane >> 5) * 4;
  const int col_l = lane & 31;
#pragma unroll
  for (int i = 0; i < 2; ++i) {
#pragma unroll
    for (int j = 0; j < 2; ++j) {
      const int colb = n0 + wn * 64 + j * 32 + col_l;
      const float bv = (OUT_PACK || blockIdx.z == 0) ? bias[colb] : 0.0f;
#pragma unroll
      for (int r = 0; r < 16; ++r) {
        const int row = m0 + wm * 64 + i * 32 + (r & 3) + 8 * (r >> 2) + cq;
        float v = acc_h[i][j][r] + acc_m[i][j][r] * (1.0f / 1024.0f) + bv;
        if (OUT_PACK) {
          v = gelu_exact(v);
          const _Float16 hi = (_Float16)v;
          const _Float16 lo = (_Float16)((v - (float)hi) * 1024.0f);
          const size_t base = amap32(row, colb, N);
          Cp[base] = h_bits(hi);
          Cp[base + 512] = h_bits(lo);
        } else {
          float* C = (blockIdx.z == 0) ? C0 : (blockIdx.z == 1) ? C1
                    : (blockIdx.z == 2) ? C2 : C3;
          C[(size_t)row * N + colb] = v;
        }
      }
    }
  }
}

// ============ update: z += (d0+d1+d2+d3) unless converged ===================
__global__ __launch_bounds__(256)
void update_kernel(float* __restrict__ z, const float* __restrict__ d0,
                   const float* __restrict__ d1, const float* __restrict__ d2,
                   const float* __restrict__ d3, int* __restrict__ mask) {
  const int row = blockIdx.x;
  const int t = threadIdx.x;
  float2 d = ((const float2*)(d0 + (size_t)row * D_DIM))[t];
  { const float2 e = ((const float2*)(d1 + (size_t)row * D_DIM))[t]; d.x += e.x; d.y += e.y; }
  { const float2 e = ((const float2*)(d2 + (size_t)row * D_DIM))[t]; d.x += e.x; d.y += e.y; }
  { const float2 e = ((const float2*)(d3 + (size_t)row * D_DIM))[t]; d.x += e.x; d.y += e.y; }
  float sq = d.x * d.x + d.y * d.y;
  sq = wave_reduce_sum(sq);
  __shared__ float sd[4];
  __shared__ int frozen_sh;
  const int lane = t & 63, wid = t >> 6;
  if (lane == 0) sd[wid] = sq;
  __syncthreads();
  if (t == 0) {
    const float dist = sqrtf(sd[0] + sd[1] + sd[2] + sd[3]);
    const int m = mask[row];
    const int newly = (dist < EPS_CONV) ? 1 : 0;
    if (!m && newly) mask[row] = 1;
    frozen_sh = m | newly;
  }
  __syncthreads();
  if (!frozen_sh) {
    float2* zp = (float2*)(z + (size_t)row * D_DIM);
    float2 zv = zp[t];
    zv.x += d.x; zv.y += d.y;
    zp[t] = zv;
  }
}

__global__ __launch_bounds__(256)
void final_kernel(const float* __restrict__ z, const float* __restrict__ clf_w,
                  const float* __restrict__ clf_b, const int* __restrict__ mask,
                  float* __restrict__ logits, float* __restrict__ maskf) {
  const int row = blockIdx.x;
  const int t = threadIdx.x;
  const float2 zv = ((const float2*)(z + (size_t)row * D_DIM))[t];
  const float2 wv = ((const float2*)clf_w)[t];
  float s = zv.x * wv.x + zv.y * wv.y;
  s = wave_reduce_sum(s);
  __shared__ float sd[4];
  const int lane = t & 63, wid = t >> 6;
  if (lane == 0) sd[wid] = s;
  __syncthreads();
  if (t == 0) {
    logits[row] = sd[0] + sd[1] + sd[2] + sd[3] + clf_b[0];
    maskf[row] = mask[row] ? 1.0f : 0.0f;
  }
}

__global__ void init_kernel(const float* __restrict__ z_init,
                            float* __restrict__ z, int* __restrict__ mask,
                            int n) {
  const int i = blockIdx.x * blockDim.x + threadIdx.x;
  if (i < n) z[i] = z_init[i];
  if (i < B_ROWS) mask[i] = 0;
}

// ============ fp32 fallback (only if ws too small) =========================
__global__ __launch_bounds__(256)
void ln_f32_kernel(const float* __restrict__ in, const float* __restrict__ g,
                   const float* __restrict__ b, float* __restrict__ out) {
  const int row = blockIdx.x;
  const int t = threadIdx.x;
  const float2 v = ((const float2*)(in + (size_t)row * D_DIM))[t];
  float s = v.x + v.y, sq = v.x * v.x + v.y * v.y;
  s = wave_reduce_sum(s); sq = wave_reduce_sum(sq);
  __shared__ float sd1[4], sd2[4], mb[2];
  const int lane = t & 63, wid = t >> 6;
  if (lane == 0) { sd1[wid] = s; sd2[wid] = sq; }
  __syncthreads();
  if (t == 0) {
    float st = sd1[0] + sd1[1] + sd1[2] + sd1[3];
    float qt = sd2[0] + sd2[1] + sd2[2] + sd2[3];
    float mean = st / (float)D_DIM;
    float var = qt / (float)D_DIM - mean * mean;
    mb[0] = mean; mb[1] = rsqrtf(var + LN_EPSF);
  }
  __syncthreads();
  const float mean = mb[0], rstd = mb[1];
  const float2 gv = ((const float2*)g)[t];
  const float2 bv = ((const float2*)b)[t];
  float2 r;
  r.x = (v.x - mean) * rstd * gv.x + bv.x;
  r.y = (v.y - mean) * rstd * gv.y + bv.y;
  ((float2*)(out + (size_t)row * D_DIM))[t] = r;
}

__global__ __launch_bounds__(256)
void update_f32_kernel(float* __restrict__ z, const float* __restrict__ delta,
                       int* __restrict__ mask) {
  const int row = blockIdx.x;
  const int t = threadIdx.x;
  const float2 d = ((const float2*)(delta + (size_t)row * D_DIM))[t];
  float sq = d.x * d.x + d.y * d.y;
  sq = wave_reduce_sum(sq);
  __shared__ float sd[4];
  __shared__ int frozen_sh;
  const int lane = t & 63, wid = t >> 6;
  if (lane == 0) sd[wid] = sq;
  __syncthreads();
  if (t == 0) {
    const float dist = sqrtf(sd[0] + sd[1] + sd[2] + sd[3]);
    const int m = mask[row];
    const int newly = (dist < EPS_CONV) ? 1 : 0;
    if (!m && newly) mask[row] = 1;
    frozen_sh = m | newly;
  }
  __syncthreads();
  if (!frozen_sh) {
    float2* zp = (float2*)(z + (size_t)row * D_DIM);
    float2 zv = zp[t];
    zv.x += d.x; zv.y += d.y;
    zp[t] = zv;
  }
}

template <int BM, int BN>
__global__ __launch_bounds__(256)
void gemm_fp32_fallback(const float* __restrict__ A, const float* __restrict__ W,
                        const float* __restrict__ bias, float* __restrict__ C,
                        int M, int N, int K, int do_gelu) {
  constexpr int BK = 8;
  constexpr int TM = BM / 16;
  constexpr int TN = BN / 16;
  __shared__ float As[BK][BM];
  __shared__ float Bs[BK][BN];
  const int tid = threadIdx.x;
  const int m0 = blockIdx.x * BM;
  const int n0 = blockIdx.y * BN;
  const int ty = tid >> 4, tx = tid & 15;
  float acc[TM][TN];
#pragma unroll
  for (int i = 0; i < TM; ++i)
#pragma unroll
    for (int j = 0; j < TN; ++j) acc[i][j] = 0.0f;
  for (int k0 = 0; k0 < K; k0 += BK) {
    if constexpr (BM == 128) {
      const int row = tid >> 1, col = (tid & 1) * 4;
      const float4 a = *(const float4*)(A + (size_t)(m0 + row) * K + k0 + col);
      As[col + 0][row] = a.x; As[col + 1][row] = a.y;
      As[col + 2][row] = a.z; As[col + 3][row] = a.w;
    } else {
      const int row = tid >> 2, col = (tid & 3) * 2;
      const float2 a = *(const float2*)(A + (size_t)(m0 + row) * K + k0 + col);
      As[col + 0][row] = a.x; As[col + 1][row] = a.y;
    }
    {
      const int row = tid >> 5, col = (tid & 31) * 4;
      const float4 w = *(const float4*)(W + (size_t)(k0 + row) * N + n0 + col);
      *(float4*)(&Bs[row][col]) = w;
    }
    __syncthreads();
#pragma unroll
    for (int kk = 0; kk < BK; ++kk) {
      float a[TM], b[TN];
#pragma unroll
      for (int i = 0; i < TM; i += 4)
        *(float4*)(a + i) = *(const float4*)(&As[kk][ty * TM + i]);
#pragma unroll
      for (int j = 0; j < TN; j += 4)
        *(float4*)(b + j) = *(const float4*)(&Bs[kk][tx * TN + j]);
#pragma unroll
      for (int i = 0; i < TM; ++i)
#pragma unroll
        for (int j = 0; j < TN; ++j) acc[i][j] = fmaf(a[i], b[j], acc[i][j]);
    }
    __syncthreads();
  }
  float bv[TN];
#pragma unroll
  for (int j = 0; j < TN; ++j) bv[j] = bias[n0 + tx * TN + j];
#pragma unroll
  for (int i = 0; i < TM; ++i) {
    const int r = m0 + ty * TM + i;
#pragma unroll
    for (int j = 0; j < TN; j += 4) {
      float4 v;
      v.x = acc[i][j + 0] + bv[j + 0]; v.y = acc[i][j + 1] + bv[j + 1];
      v.z = acc[i][j + 2] + bv[j + 2]; v.w = acc[i][j + 3] + bv[j + 3];
      if (do_gelu) {
        v.x = gelu_exact(v.x); v.y = gelu_exact(v.y);
        v.z = gelu_exact(v.z); v.w = gelu_exact(v.w);
      }
      *(float4*)(C + (size_t)r * N + n0 + tx * TN + j) = v;
    }
  }
}

// ============ launch =======================================================
extern "C" void kernel_launch(void* const* d_in, const int* in_sizes, int n_in,
                              void* d_out, int out_size, void* d_ws,
                              size_t ws_size, hipStream_t stream) {
  const float* z_init = (const float*)d_in[0];
  const float* ln1_g  = (const float*)d_in[1];
  const float* ln1_b  = (const float*)d_in[2];
  const float* w1     = (const float*)d_in[3];
  const float* b1     = (const float*)d_in[4];
  const float* w2     = (const float*)d_in[5];
  const float* b2     = (const float*)d_in[6];
  const float* ln2_g  = (const float*)d_in[7];
  const float* ln2_b  = (const float*)d_in[8];
  const float* w3     = (const float*)d_in[9];
  const float* b3     = (const float*)d_in[10];
  const float* w4     = (const float*)d_in[11];
  const float* b4     = (const float*)d_in[12];
  const float* clf_w  = (const float*)d_in[13];
  const float* clf_b  = (const float*)d_in[14];

  float* out    = (float*)d_out;
  float* logits = out;
  float* maskf  = out + B_ROWS;
  float* z      = out + 2 * B_ROWS;   // [B,D] in d_out

  const size_t BD = (size_t)B_ROWS * D_DIM;
  const size_t BH = (size_t)B_ROWS * H_DIM;
  const size_t WSZ = (size_t)D_DIM * H_DIM;

  // layout: xh | hp | y0..y3 | w1p..w4p | mask
  ushort_t* xh  = (ushort_t*)d_ws;        // [B,D] hi/lo planes
  ushort_t* hp  = xh + BD * 2;            // [B,H] hi/lo planes
  float*    y0  = (float*)(hp + BH * 2);  // 4 split-K partial slabs [B,D]
  float*    y1  = y0 + BD;
  float*    y2  = y1 + BD;
  float*    y3  = y2 + BD;
  ushort_t* w1p = (ushort_t*)(y3 + BD);   // each WSZ*2 ushorts
  ushort_t* w2p = w1p + WSZ * 2;
  ushort_t* w3p = w2p + WSZ * 2;
  ushort_t* w4p = w3p + WSZ * 2;
  int*     mask = (int*)(w4p + WSZ * 2);
  const size_t need = (uintptr_t)((char*)(mask + B_ROWS) - (char*)d_ws) + 256;

  init_kernel<<<(int)((BD + 255) / 256), 256, 0, stream>>>(z_init, z, mask,
                                                           (int)BD);

  if (ws_size >= need) {
    const dim3 tb(32, 8);
    transpose_split_kernel<<<dim3(H_DIM / 32, D_DIM / 32), tb, 0, stream>>>(w1, w1p, D_DIM, H_DIM);
    transpose_split_kernel<<<dim3(D_DIM / 32, H_DIM / 32), tb, 0, stream>>>(w2, w2p, H_DIM, D_DIM);
    transpose_split_kernel<<<dim3(H_DIM / 32, D_DIM / 32), tb, 0, stream>>>(w3, w3p, D_DIM, H_DIM);
    transpose_split_kernel<<<dim3(D_DIM / 32, H_DIM / 32), tb, 0, stream>>>(w4, w4p, H_DIM, D_DIM);

    const dim3 g_up(B_ROWS / 128, H_DIM / 128, 1);   // 32x16 = 512 blocks
    const dim3 g_dn(B_ROWS / 128, D_DIM / 128, 4);   // 32x4x4 = 512 blocks
    for (int s = 0; s < N_STEPS; ++s) {
      ln_pack_kernel<<<B_ROWS, 256, 0, stream>>>(z, nullptr, nullptr, nullptr,
                                                 ln1_g, ln1_b, xh);
      gemm32<true><<<g_up, 256, 0, stream>>>(
          xh, w1p, b1, hp, nullptr, nullptr, nullptr, nullptr,
          B_ROWS, H_DIM, D_DIM, D_DIM);
      gemm32<false><<<g_dn, 256, 0, stream>>>(
          hp, w2p, b2, nullptr, y0, y1, y2, y3,
          B_ROWS, D_DIM, H_DIM, H_DIM / 4);
      ln_pack_kernel<<<B_ROWS, 256, 0, stream>>>(y0, y1, y2, y3,
                                                 ln2_g, ln2_b, xh);
      gemm32<true><<<g_up, 256, 0, stream>>>(
          xh, w3p, b3, hp, nullptr, nullptr, nullptr, nullptr,
          B_ROWS, H_DIM, D_DIM, D_DIM);
      gemm32<false><<<g_dn, 256, 0, stream>>>(
          hp, w4p, b4, nullptr, y0, y1, y2, y3,
          B_ROWS, D_DIM, H_DIM, H_DIM / 4);
      update_kernel<<<B_ROWS, 256, 0, stream>>>(z, y0, y1, y2, y3, mask);
    }
  } else {
    // fallback: fp32 pipeline
    float* x  = (float*)d_ws;
    float* yf = x + BD;
    float* h  = yf + BD;
    int* mask_fb = (int*)(h + BH);
    mask = mask_fb;
    const dim3 g_up(B_ROWS / 128, H_DIM / 128);
    const dim3 g_dn(B_ROWS / 64, D_DIM / 128);
    for (int s = 0; s < N_STEPS; ++s) {
      ln_f32_kernel<<<B_ROWS, 256, 0, stream>>>(z, ln1_g, ln1_b, x);
      gemm_fp32_fallback<128, 128><<<g_up, 256, 0, stream>>>(x, w1, b1, h, B_ROWS, H_DIM, D_DIM, 1);
      gemm_fp32_fallback<64, 128><<<g_dn, 256, 0, stream>>>(h, w2, b2, yf, B_ROWS, D_DIM, H_DIM, 0);
      ln_f32_kernel<<<B_ROWS, 256, 0, stream>>>(yf, ln2_g, ln2_b, x);
      gemm_fp32_fallback<128, 128><<<g_up, 256, 0, stream>>>(x, w3, b3, h, B_ROWS, H_DIM, D_DIM, 1);
      gemm_fp32_fallback<64, 128><<<g_dn, 256, 0, stream>>>(h, w4, b4, yf, B_ROWS, D_DIM, H_DIM, 0);
      update_f32_kernel<<<B_ROWS, 256, 0, stream>>>(z, yf, mask);
    }
  }
  final_kernel<<<B_ROWS, 256, 0, stream>>>(z, clf_w, clf_b, mask, logits, maskf);
}

// Round 9
// 5653.252 us; speedup vs baseline: 1.9235x; 1.0609x over previous
//
#include <hip/hip_runtime.h>

#define B_ROWS  4096
#define D_DIM   512
#define H_DIM   2048
#define N_STEPS 32
#define EPS_CONV 0.01f
#define LN_EPSF  1e-5f

typedef __attribute__((ext_vector_type(16))) float f32x16;
typedef __attribute__((ext_vector_type(8))) _Float16 h16x8;
typedef unsigned short ushort_t;
typedef unsigned int uint32;

__device__ __forceinline__ float wave_reduce_sum(float v) {
#pragma unroll
  for (int o = 32; o > 0; o >>= 1) v += __shfl_down(v, o, 64);
  return v;
}

__device__ __forceinline__ float gelu_exact(float v) {
  return 0.5f * v * (1.0f + erff(v * 0.7071067811865476f));
}

__device__ __forceinline__ ushort_t h_bits(_Float16 h) {
  union { _Float16 f; ushort_t u; } c; c.f = h; return c.u;
}

// 32x32x16-MFMA fragment-plane tiling (ushort units).
// Tile = 32 rows x 16 k: 512-half hi plane + 512-half lo plane (1024/tile).
//   lane = ((k>>3)&1)*32 + (row&31); in-lane idx = k&7.
//   hi at tile*1024 + lane*8 + (k&7), lo at +512.
// A wave's fragment load = ONE lane-coalesced 1KB dwordx4 per plane.
__device__ __forceinline__ size_t amap32(int row, int k, int K) {
  return ((size_t)((row >> 5) * (K >> 4) + (k >> 4)) << 10) +
         ((size_t)((((k >> 3) & 1) << 5) | (row & 31)) << 3) + (k & 7);
}

// ============ LayerNorm (sum of up to 4 inputs) -> hi/lo planes ============
__global__ __launch_bounds__(256)
void ln_pack_kernel(const float* in0, const float* in1, const float* in2,
                    const float* in3, const float* g, const float* b,
                    ushort_t* outp) {
  const int row = blockIdx.x;
  const int t = threadIdx.x;
  float2 v = ((const float2*)(in0 + (size_t)row * D_DIM))[t];
  if (in1) { const float2 w = ((const float2*)(in1 + (size_t)row * D_DIM))[t]; v.x += w.x; v.y += w.y; }
  if (in2) { const float2 w = ((const float2*)(in2 + (size_t)row * D_DIM))[t]; v.x += w.x; v.y += w.y; }
  if (in3) { const float2 w = ((const float2*)(in3 + (size_t)row * D_DIM))[t]; v.x += w.x; v.y += w.y; }
  float s  = v.x + v.y;
  float sq = v.x * v.x + v.y * v.y;
  s  = wave_reduce_sum(s);
  sq = wave_reduce_sum(sq);
  __shared__ float sd1[4], sd2[4], mb[2];
  const int lane = t & 63, wid = t >> 6;
  if (lane == 0) { sd1[wid] = s; sd2[wid] = sq; }
  __syncthreads();
  if (t == 0) {
    float st = sd1[0] + sd1[1] + sd1[2] + sd1[3];
    float qt = sd2[0] + sd2[1] + sd2[2] + sd2[3];
    float mean = st * (1.0f / (float)D_DIM);
    float var  = qt * (1.0f / (float)D_DIM) - mean * mean;
    mb[0] = mean;
    mb[1] = rsqrtf(var + LN_EPSF);
  }
  __syncthreads();
  const float mean = mb[0], rstd = mb[1];
  const float2 gv = ((const float2*)g)[t];
  const float2 bv = ((const float2*)b)[t];
  const float r0 = (v.x - mean) * rstd * gv.x + bv.x;
  const float r1 = (v.y - mean) * rstd * gv.y + bv.y;
  const _Float16 h0 = (_Float16)r0, h1 = (_Float16)r1;
  const _Float16 l0 = (_Float16)((r0 - (float)h0) * 1024.0f);
  const _Float16 l1 = (_Float16)((r1 - (float)h1) * 1024.0f);
  const size_t base = amap32(row, 2 * t, D_DIM);   // k=2t,2t+1 same lane slot
  union { _Float16 f[2]; uint32 u; } ph, pl;
  ph.f[0] = h0; ph.f[1] = h1;
  pl.f[0] = l0; pl.f[1] = l1;
  *(uint32*)(outp + base) = ph.u;
  *(uint32*)(outp + base + 512) = pl.u;
}

// ============ weight transpose + split into hi/lo planes (one-time) ========
__global__ __launch_bounds__(256)
void transpose_split_kernel(const float* __restrict__ w,
                            ushort_t* __restrict__ wp, int K, int N) {
  __shared__ float t[32][33];
  const int tx = threadIdx.x;   // 0..31
  const int ty = threadIdx.y;   // 0..7
  const int n_base = blockIdx.x * 32;
  const int k_base = blockIdx.y * 32;
#pragma unroll
  for (int r = 0; r < 4; ++r)
    t[ty + r * 8][tx] = w[(size_t)(k_base + ty + r * 8) * N + n_base + tx];
  __syncthreads();
#pragma unroll
  for (int r = 0; r < 4; ++r) {
    const int n = n_base + ty + r * 8;
    const int k = k_base + tx;
    const float v = t[tx][ty + r * 8];
    const _Float16 hi = (_Float16)v;
    const _Float16 lo = (_Float16)((v - (float)hi) * 1024.0f);
    const size_t base = amap32(n, k, K);
    wp[base] = h_bits(hi);
    wp[base + 512] = h_bits(lo);
  }
}

// ============ zero-LDS 32x32x16 f16x3 GEMM, 3-bank pipelined ===============
// A, W: f16 hi/lo fragment planes. Block 128x128, 4 waves 2x2, k-step 16.
// kc MUST be 512 (NKT=32, fully unrolled). Prefetch distance = 2 k-steps.
// OUT_PACK: C -> gelu -> hi/lo planes (next GEMM's A). else: fp32 partial to
// Cz[blockIdx.z], bias added only on z==0.
template <bool OUT_PACK>
__global__ __launch_bounds__(256, 2)
void gemm32(const ushort_t* __restrict__ Ah, const ushort_t* __restrict__ Wh,
            const float* __restrict__ bias, ushort_t* __restrict__ Cp,
            float* __restrict__ C0, float* __restrict__ C1,
            float* __restrict__ C2, float* __restrict__ C3,
            int M, int N, int K, int kc) {
  constexpr int NKT = 32;          // k-steps per block (kc == 512)
  const int KT = K >> 4;           // k-steps total

  const int tid = threadIdx.x;
  const int lane = tid & 63;
  const int wid = tid >> 6;
  const int wm = wid >> 1;
  const int wn = wid & 1;

  const int m0 = blockIdx.x * 128;
  const int n0 = blockIdx.y * 128;
  const int kz0 = blockIdx.z * NKT;   // in k-steps

  const ushort_t* pa[2];
#pragma unroll
  for (int i = 0; i < 2; ++i) {
    const int tm = (m0 >> 5) + wm * 2 + i;
    pa[i] = Ah + ((size_t)(tm * KT + kz0) << 10) + lane * 8;
  }
  const ushort_t* pb[2];
#pragma unroll
  for (int j = 0; j < 2; ++j) {
    const int tn = (n0 >> 5) + wn * 2 + j;
    pb[j] = Wh + ((size_t)(tn * KT + kz0) << 10) + lane * 8;
  }

  f32x16 acc_h[2][2], acc_m[2][2];
#pragma unroll
  for (int i = 0; i < 2; ++i)
#pragma unroll
    for (int j = 0; j < 2; ++j) {
      acc_h[i][j] = (f32x16)(0.0f);
      acc_m[i][j] = (f32x16)(0.0f);
    }

  // 3 register banks; pointers always aim at the next k-step to load.
  h16x8 bkAh[3][2], bkAl[3][2], bkBh[3][2], bkBl[3][2];

#define LOADBANK(bb)                                                          \
  _Pragma("unroll") for (int i = 0; i < 2; ++i) {                             \
    bkAh[bb][i] = *(const h16x8*)(pa[i]);                                     \
    bkAl[bb][i] = *(const h16x8*)(pa[i] + 512);                               \
    pa[i] += 1024;                                                            \
  }                                                                           \
  _Pragma("unroll") for (int j = 0; j < 2; ++j) {                             \
    bkBh[bb][j] = *(const h16x8*)(pb[j]);                                     \
    bkBl[bb][j] = *(const h16x8*)(pb[j] + 512);                               \
    pb[j] += 1024;                                                            \
  }

#define MFMAB(bb)                                                             \
  _Pragma("unroll") for (int i = 0; i < 2; ++i)                               \
  _Pragma("unroll") for (int j = 0; j < 2; ++j) {                             \
    acc_h[i][j] = __builtin_amdgcn_mfma_f32_32x32x16_f16(                     \
        bkAh[bb][i], bkBh[bb][j], acc_h[i][j], 0, 0, 0);                      \
    acc_m[i][j] = __builtin_amdgcn_mfma_f32_32x32x16_f16(                     \
        bkAl[bb][i], bkBh[bb][j], acc_m[i][j], 0, 0, 0);                      \
    acc_m[i][j] = __builtin_amdgcn_mfma_f32_32x32x16_f16(                     \
        bkAh[bb][i], bkBl[bb][j], acc_m[i][j], 0, 0, 0);                      \
  }

  LOADBANK(0)
  LOADBANK(1)
#pragma unroll
  for (int kt = 0; kt < NKT; ++kt) {      // fully unrolled; banks static
    if (kt < NKT - 2) {
      switch ((kt + 2) % 3) {
        case 0: { LOADBANK(0) } break;
        case 1: { LOADBANK(1) } break;
        default: { LOADBANK(2) } break;
      }
    }
    switch (kt % 3) {
      case 0: { MFMAB(0) } break;
      case 1: { MFMAB(1) } break;
      default: { MFMAB(2) } break;
    }
  }
#undef LOADBANK
#undef MFMAB

  // ---- epilogue: C/D map col=lane&31, row=(r&3)+8*(r>>2)+4*(lane>>5) ----
  const int cq = (lane >> 5) * 4;
  const int col_l = lane & 31;
#pragma unroll
  for (int i = 0; i < 2; ++i) {
#pragma unroll
    for (int j = 0; j < 2; ++j) {
      const int colb = n0 + wn * 64 + j * 32 + col_l;
      const float bv = (OUT_PACK || blockIdx.z == 0) ? bias[colb] : 0.0f;
#pragma unroll
      for (int r = 0; r < 16; ++r) {
        const int row = m0 + wm * 64 + i * 32 + (r & 3) + 8 * (r >> 2) + cq;
        float v = acc_h[i][j][r] + acc_m[i][j][r] * (1.0f / 1024.0f) + bv;
        if (OUT_PACK) {
          v = gelu_exact(v);
          const _Float16 hi = (_Float16)v;
          const _Float16 lo = (_Float16)((v - (float)hi) * 1024.0f);
          const size_t base = amap32(row, colb, N);
          Cp[base] = h_bits(hi);
          Cp[base + 512] = h_bits(lo);
        } else {
          float* C = (blockIdx.z == 0) ? C0 : (blockIdx.z == 1) ? C1
                    : (blockIdx.z == 2) ? C2 : C3;
          C[(size_t)row * N + colb] = v;
        }
      }
    }
  }
}

// ============ update: z += (d0+d1+d2+d3) unless converged ===================
__global__ __launch_bounds__(256)
void update_kernel(float* __restrict__ z, const float* __restrict__ d0,
                   const float* __restrict__ d1, const float* __restrict__ d2,
                   const float* __restrict__ d3, int* __restrict__ mask) {
  const int row = blockIdx.x;
  const int t = threadIdx.x;
  float2 d = ((const float2*)(d0 + (size_t)row * D_DIM))[t];
  { const float2 e = ((const float2*)(d1 + (size_t)row * D_DIM))[t]; d.x += e.x; d.y += e.y; }
  { const float2 e = ((const float2*)(d2 + (size_t)row * D_DIM))[t]; d.x += e.x; d.y += e.y; }
  { const float2 e = ((const float2*)(d3 + (size_t)row * D_DIM))[t]; d.x += e.x; d.y += e.y; }
  float sq = d.x * d.x + d.y * d.y;
  sq = wave_reduce_sum(sq);
  __shared__ float sd[4];
  __shared__ int frozen_sh;
  const int lane = t & 63, wid = t >> 6;
  if (lane == 0) sd[wid] = sq;
  __syncthreads();
  if (t == 0) {
    const float dist = sqrtf(sd[0] + sd[1] + sd[2] + sd[3]);
    const int m = mask[row];
    const int newly = (dist < EPS_CONV) ? 1 : 0;
    if (!m && newly) mask[row] = 1;
    frozen_sh = m | newly;
  }
  __syncthreads();
  if (!frozen_sh) {
    float2* zp = (float2*)(z + (size_t)row * D_DIM);
    float2 zv = zp[t];
    zv.x += d.x; zv.y += d.y;
    zp[t] = zv;
  }
}

__global__ __launch_bounds__(256)
void final_kernel(const float* __restrict__ z, const float* __restrict__ clf_w,
                  const float* __restrict__ clf_b, const int* __restrict__ mask,
                  float* __restrict__ logits, float* __restrict__ maskf) {
  const int row = blockIdx.x;
  const int t = threadIdx.x;
  const float2 zv = ((const float2*)(z + (size_t)row * D_DIM))[t];
  const float2 wv = ((const float2*)clf_w)[t];
  float s = zv.x * wv.x + zv.y * wv.y;
  s = wave_reduce_sum(s);
  __shared__ float sd[4];
  const int lane = t & 63, wid = t >> 6;
  if (lane == 0) sd[wid] = s;
  __syncthreads();
  if (t == 0) {
    logits[row] = sd[0] + sd[1] + sd[2] + sd[3] + clf_b[0];
    maskf[row] = mask[row] ? 1.0f : 0.0f;
  }
}

__global__ void init_kernel(const float* __restrict__ z_init,
                            float* __restrict__ z, int* __restrict__ mask,
                            int n) {
  const int i = blockIdx.x * blockDim.x + threadIdx.x;
  if (i < n) z[i] = z_init[i];
  if (i < B_ROWS) mask[i] = 0;
}

// ============ fp32 fallback (only if ws too small) =========================
__global__ __launch_bounds__(256)
void ln_f32_kernel(const float* __restrict__ in, const float* __restrict__ g,
                   const float* __restrict__ b, float* __restrict__ out) {
  const int row = blockIdx.x;
  const int t = threadIdx.x;
  const float2 v = ((const float2*)(in + (size_t)row * D_DIM))[t];
  float s = v.x + v.y, sq = v.x * v.x + v.y * v.y;
  s = wave_reduce_sum(s); sq = wave_reduce_sum(sq);
  __shared__ float sd1[4], sd2[4], mb[2];
  const int lane = t & 63, wid = t >> 6;
  if (lane == 0) { sd1[wid] = s; sd2[wid] = sq; }
  __syncthreads();
  if (t == 0) {
    float st = sd1[0] + sd1[1] + sd1[2] + sd1[3];
    float qt = sd2[0] + sd2[1] + sd2[2] + sd2[3];
    float mean = st / (float)D_DIM;
    float var = qt / (float)D_DIM - mean * mean;
    mb[0] = mean; mb[1] = rsqrtf(var + LN_EPSF);
  }
  __syncthreads();
  const float mean = mb[0], rstd = mb[1];
  const float2 gv = ((const float2*)g)[t];
  const float2 bv = ((const float2*)b)[t];
  float2 r;
  r.x = (v.x - mean) * rstd * gv.x + bv.x;
  r.y = (v.y - mean) * rstd * gv.y + bv.y;
  ((float2*)(out + (size_t)row * D_DIM))[t] = r;
}

__global__ __launch_bounds__(256)
void update_f32_kernel(float* __restrict__ z, const float* __restrict__ delta,
                       int* __restrict__ mask) {
  const int row = blockIdx.x;
  const int t = threadIdx.x;
  const float2 d = ((const float2*)(delta + (size_t)row * D_DIM))[t];
  float sq = d.x * d.x + d.y * d.y;
  sq = wave_reduce_sum(sq);
  __shared__ float sd[4];
  __shared__ int frozen_sh;
  const int lane = t & 63, wid = t >> 6;
  if (lane == 0) sd[wid] = sq;
  __syncthreads();
  if (t == 0) {
    const float dist = sqrtf(sd[0] + sd[1] + sd[2] + sd[3]);
    const int m = mask[row];
    const int newly = (dist < EPS_CONV) ? 1 : 0;
    if (!m && newly) mask[row] = 1;
    frozen_sh = m | newly;
  }
  __syncthreads();
  if (!frozen_sh) {
    float2* zp = (float2*)(z + (size_t)row * D_DIM);
    float2 zv = zp[t];
    zv.x += d.x; zv.y += d.y;
    zp[t] = zv;
  }
}

template <int BM, int BN>
__global__ __launch_bounds__(256)
void gemm_fp32_fallback(const float* __restrict__ A, const float* __restrict__ W,
                        const float* __restrict__ bias, float* __restrict__ C,
                        int M, int N, int K, int do_gelu) {
  constexpr int BK = 8;
  constexpr int TM = BM / 16;
  constexpr int TN = BN / 16;
  __shared__ float As[BK][BM];
  __shared__ float Bs[BK][BN];
  const int tid = threadIdx.x;
  const int m0 = blockIdx.x * BM;
  const int n0 = blockIdx.y * BN;
  const int ty = tid >> 4, tx = tid & 15;
  float acc[TM][TN];
#pragma unroll
  for (int i = 0; i < TM; ++i)
#pragma unroll
    for (int j = 0; j < TN; ++j) acc[i][j] = 0.0f;
  for (int k0 = 0; k0 < K; k0 += BK) {
    if constexpr (BM == 128) {
      const int row = tid >> 1, col = (tid & 1) * 4;
      const float4 a = *(const float4*)(A + (size_t)(m0 + row) * K + k0 + col);
      As[col + 0][row] = a.x; As[col + 1][row] = a.y;
      As[col + 2][row] = a.z; As[col + 3][row] = a.w;
    } else {
      const int row = tid >> 2, col = (tid & 3) * 2;
      const float2 a = *(const float2*)(A + (size_t)(m0 + row) * K + k0 + col);
      As[col + 0][row] = a.x; As[col + 1][row] = a.y;
    }
    {
      const int row = tid >> 5, col = (tid & 31) * 4;
      const float4 w = *(const float4*)(W + (size_t)(k0 + row) * N + n0 + col);
      *(float4*)(&Bs[row][col]) = w;
    }
    __syncthreads();
#pragma unroll
    for (int kk = 0; kk < BK; ++kk) {
      float a[TM], b[TN];
#pragma unroll
      for (int i = 0; i < TM; i += 4)
        *(float4*)(a + i) = *(const float4*)(&As[kk][ty * TM + i]);
#pragma unroll
      for (int j = 0; j < TN; j += 4)
        *(float4*)(b + j) = *(const float4*)(&Bs[kk][tx * TN + j]);
#pragma unroll
      for (int i = 0; i < TM; ++i)
#pragma unroll
        for (int j = 0; j < TN; ++j) acc[i][j] = fmaf(a[i], b[j], acc[i][j]);
    }
    __syncthreads();
  }
  float bv[TN];
#pragma unroll
  for (int j = 0; j < TN; ++j) bv[j] = bias[n0 + tx * TN + j];
#pragma unroll
  for (int i = 0; i < TM; ++i) {
    const int r = m0 + ty * TM + i;
#pragma unroll
    for (int j = 0; j < TN; j += 4) {
      float4 v;
      v.x = acc[i][j + 0] + bv[j + 0]; v.y = acc[i][j + 1] + bv[j + 1];
      v.z = acc[i][j + 2] + bv[j + 2]; v.w = acc[i][j + 3] + bv[j + 3];
      if (do_gelu) {
        v.x = gelu_exact(v.x); v.y = gelu_exact(v.y);
        v.z = gelu_exact(v.z); v.w = gelu_exact(v.w);
      }
      *(float4*)(C + (size_t)r * N + n0 + tx * TN + j) = v;
    }
  }
}

// ============ launch =======================================================
extern "C" void kernel_launch(void* const* d_in, const int* in_sizes, int n_in,
                              void* d_out, int out_size, void* d_ws,
                              size_t ws_size, hipStream_t stream) {
  const float* z_init = (const float*)d_in[0];
  const float* ln1_g  = (const float*)d_in[1];
  const float* ln1_b  = (const float*)d_in[2];
  const float* w1     = (const float*)d_in[3];
  const float* b1     = (const float*)d_in[4];
  const float* w2     = (const float*)d_in[5];
  const float* b2     = (const float*)d_in[6];
  const float* ln2_g  = (const float*)d_in[7];
  const float* ln2_b  = (const float*)d_in[8];
  const float* w3     = (const float*)d_in[9];
  const float* b3     = (const float*)d_in[10];
  const float* w4     = (const float*)d_in[11];
  const float* b4     = (const float*)d_in[12];
  const float* clf_w  = (const float*)d_in[13];
  const float* clf_b  = (const float*)d_in[14];

  float* out    = (float*)d_out;
  float* logits = out;
  float* maskf  = out + B_ROWS;
  float* z      = out + 2 * B_ROWS;   // [B,D] in d_out

  const size_t BD = (size_t)B_ROWS * D_DIM;
  const size_t BH = (size_t)B_ROWS * H_DIM;
  const size_t WSZ = (size_t)D_DIM * H_DIM;

  // layout: xh | hp | y0..y3 | w1p..w4p | mask
  ushort_t* xh  = (ushort_t*)d_ws;        // [B,D] hi/lo planes
  ushort_t* hp  = xh + BD * 2;            // [B,H] hi/lo planes
  float*    y0  = (float*)(hp + BH * 2);  // 4 split-K partial slabs [B,D]
  float*    y1  = y0 + BD;
  float*    y2  = y1 + BD;
  float*    y3  = y2 + BD;
  ushort_t* w1p = (ushort_t*)(y3 + BD);   // each WSZ*2 ushorts
  ushort_t* w2p = w1p + WSZ * 2;
  ushort_t* w3p = w2p + WSZ * 2;
  ushort_t* w4p = w3p + WSZ * 2;
  int*     mask = (int*)(w4p + WSZ * 2);
  const size_t need = (uintptr_t)((char*)(mask + B_ROWS) - (char*)d_ws) + 256;

  init_kernel<<<(int)((BD + 255) / 256), 256, 0, stream>>>(z_init, z, mask,
                                                           (int)BD);

  if (ws_size >= need) {
    const dim3 tb(32, 8);
    transpose_split_kernel<<<dim3(H_DIM / 32, D_DIM / 32), tb, 0, stream>>>(w1, w1p, D_DIM, H_DIM);
    transpose_split_kernel<<<dim3(D_DIM / 32, H_DIM / 32), tb, 0, stream>>>(w2, w2p, H_DIM, D_DIM);
    transpose_split_kernel<<<dim3(H_DIM / 32, D_DIM / 32), tb, 0, stream>>>(w3, w3p, D_DIM, H_DIM);
    transpose_split_kernel<<<dim3(D_DIM / 32, H_DIM / 32), tb, 0, stream>>>(w4, w4p, H_DIM, D_DIM);

    const dim3 g_up(B_ROWS / 128, H_DIM / 128, 1);   // 32x16 = 512 blocks
    const dim3 g_dn(B_ROWS / 128, D_DIM / 128, 4);   // 32x4x4 = 512 blocks
    for (int s = 0; s < N_STEPS; ++s) {
      ln_pack_kernel<<<B_ROWS, 256, 0, stream>>>(z, nullptr, nullptr, nullptr,
                                                 ln1_g, ln1_b, xh);
      gemm32<true><<<g_up, 256, 0, stream>>>(
          xh, w1p, b1, hp, nullptr, nullptr, nullptr, nullptr,
          B_ROWS, H_DIM, D_DIM, D_DIM);
      gemm32<false><<<g_dn, 256, 0, stream>>>(
          hp, w2p, b2, nullptr, y0, y1, y2, y3,
          B_ROWS, D_DIM, H_DIM, H_DIM / 4);
      ln_pack_kernel<<<B_ROWS, 256, 0, stream>>>(y0, y1, y2, y3,
                                                 ln2_g, ln2_b, xh);
      gemm32<true><<<g_up, 256, 0, stream>>>(
          xh, w3p, b3, hp, nullptr, nullptr, nullptr, nullptr,
          B_ROWS, H_DIM, D_DIM, D_DIM);
      gemm32<false><<<g_dn, 256, 0, stream>>>(
          hp, w4p, b4, nullptr, y0, y1, y2, y3,
          B_ROWS, D_DIM, H_DIM, H_DIM / 4);
      update_kernel<<<B_ROWS, 256, 0, stream>>>(z, y0, y1, y2, y3, mask);
    }
  } else {
    // fallback: fp32 pipeline
    float* x  = (float*)d_ws;
    float* yf = x + BD;
    float* h  = yf + BD;
    int* mask_fb = (int*)(h + BH);
    mask = mask_fb;
    const dim3 g_up(B_ROWS / 128, H_DIM / 128);
    const dim3 g_dn(B_ROWS / 64, D_DIM / 128);
    for (int s = 0; s < N_STEPS; ++s) {
      ln_f32_kernel<<<B_ROWS, 256, 0, stream>>>(z, ln1_g, ln1_b, x);
      gemm_fp32_fallback<128, 128><<<g_up, 256, 0, stream>>>(x, w1, b1, h, B_ROWS, H_DIM, D_DIM, 1);
      gemm_fp32_fallback<64, 128><<<g_dn, 256, 0, stream>>>(h, w2, b2, yf, B_ROWS, D_DIM, H_DIM, 0);
      ln_f32_kernel<<<B_ROWS, 256, 0, stream>>>(yf, ln2_g, ln2_b, x);
      gemm_fp32_fallback<128, 128><<<g_up, 256, 0, stream>>>(x, w3, b3, h, B_ROWS, H_DIM, D_DIM, 1);
      gemm_fp32_fallback<64, 128><<<g_dn, 256, 0, stream>>>(h, w4, b4, yf, B_ROWS, D_DIM, H_DIM, 0);
      update_f32_kernel<<<B_ROWS, 256, 0, stream>>>(z, yf, mask);
    }
  }
  final_kernel<<<B_ROWS, 256, 0, stream>>>(z, clf_w, clf_b, mask, logits, maskf);
}